// Round 1
// baseline (3005.829 us; speedup 1.0000x reference)
//
#include <hip/hip_runtime.h>
#include <hip/hip_bf16.h>

#define B_ 4
#define S_IN 32768
#define C1V 128
#define L1V 16384
#define C2V 256
#define L2V 8192
#define C3V 512
#define L3V 4096
#define VOCABV 2048
#define KCB 4

// ---------------- conv1: [B,1,S] -> [B,128,16384], k=7 s=2 p=3, relu ----------------
__global__ void conv1_kernel(const float* __restrict__ x, const float* __restrict__ w,
                             const float* __restrict__ bias, float* __restrict__ out) {
    __shared__ float xs[2 * 256 + 6];
    __shared__ float ws[7];
    const int l0 = blockIdx.x * 256;
    const int co = blockIdx.y;
    const int b  = blockIdx.z;
    const int tid = threadIdx.x;
    const float* xb = x + (size_t)b * S_IN;
    for (int n = tid; n < 2 * 256 + 6; n += 256) {
        int p = 2 * l0 - 3 + n;
        xs[n] = (p >= 0 && p < S_IN) ? xb[p] : 0.f;
    }
    if (tid < 7) ws[tid] = w[co * 7 + tid];
    __syncthreads();
    float acc = bias[co];
    const int base = 2 * tid;
#pragma unroll
    for (int t = 0; t < 7; ++t) acc = fmaf(ws[t], xs[base + t], acc);
    acc = fmaxf(acc, 0.f);
    out[((size_t)(b * C1V + co)) * L1V + l0 + tid] = acc;
}

// ---------------- weight transpose: w[co][ci][t] -> wt[ci][t][co] ----------------
__global__ void transpose_w_kernel(const float* __restrict__ w, float* __restrict__ wt,
                                   int cin, int cout) {
    int n = blockIdx.x * blockDim.x + threadIdx.x;
    int total = cin * 7 * cout;
    if (n >= total) return;
    int co = n % cout;
    int t  = (n / cout) % 7;
    int ci = n / (cout * 7);
    wt[n] = w[(co * cin + ci) * 7 + t];
}

// ---------------- tiled conv (k=7, s=2, p=3): implicit GEMM ----------------
// 64 co x 64 l tile per block, 256 threads, 4x4 micro-tile.
// Input staged in LDS split by position parity so stride-2 reads are contiguous.
// Weights read from global in transposed layout [ci][t][co] (coalesced float4).
template <int CIN, int COUT, int LIN, bool RELU, bool TRANS>
__global__ __launch_bounds__(256) void conv_tiled_kernel(
    const float* __restrict__ in, const float* __restrict__ wt,
    const float* __restrict__ bias, float* __restrict__ out) {
    constexpr int LOUT = LIN / 2;
    __shared__ float xs[2][16][68];
    const int tid = threadIdx.x;
    const int tx = tid & 15;   // co group
    const int ty = tid >> 4;   // l group
    const int l0  = blockIdx.x * 64;
    const int co0 = blockIdx.y * 64;
    const int b   = blockIdx.z;
    const float* inb = in + (size_t)b * CIN * LIN;

    float acc[4][4];  // [i=co][j=l]
#pragma unroll
    for (int i = 0; i < 4; ++i)
#pragma unroll
        for (int j = 0; j < 4; ++j) acc[i][j] = 0.f;

    for (int c0 = 0; c0 < CIN; c0 += 16) {
        __syncthreads();
        // stage: xs[par][ci][q] = in[ci][2*l0 + 2*q + par - 3]
        for (int n = tid; n < 2 * 16 * 68; n += 256) {
            int q   = n % 68;
            int rc  = n / 68;
            int ci  = rc & 15;
            int par = rc >> 4;
            int p = 2 * l0 + 2 * q + par - 3;
            float v = (p >= 0 && p < LIN) ? inb[(size_t)(c0 + ci) * LIN + p] : 0.f;
            xs[par][ci][q] = v;
        }
        __syncthreads();
#pragma unroll 2
        for (int ci = 0; ci < 16; ++ci) {
            const float4 e0 = *(const float4*)&xs[0][ci][4 * ty];
            const float4 e1 = *(const float4*)&xs[0][ci][4 * ty + 4];
            const float4 o0 = *(const float4*)&xs[1][ci][4 * ty];
            const float4 o1 = *(const float4*)&xs[1][ci][4 * ty + 4];
            const float xe[8] = {e0.x, e0.y, e0.z, e0.w, e1.x, e1.y, e1.z, e1.w};
            const float xo[8] = {o0.x, o0.y, o0.z, o0.w, o1.x, o1.y, o1.z, o1.w};
#pragma unroll
            for (int t = 0; t < 7; ++t) {
                const float* xx = (t & 1) ? xo : xe;
                const int t2 = t >> 1;
                const float4 w4 = *(const float4*)&wt[((size_t)(c0 + ci) * 7 + t) * COUT + co0 + 4 * tx];
                const float wv[4] = {w4.x, w4.y, w4.z, w4.w};
#pragma unroll
                for (int i = 0; i < 4; ++i)
#pragma unroll
                    for (int j = 0; j < 4; ++j)
                        acc[i][j] = fmaf(wv[i], xx[t2 + j], acc[i][j]);
            }
        }
    }
    // epilogue
    float bv[4];
#pragma unroll
    for (int i = 0; i < 4; ++i) bv[i] = bias[co0 + 4 * tx + i];
    if (!TRANS) {
#pragma unroll
        for (int i = 0; i < 4; ++i) {
            const int co = co0 + 4 * tx + i;
            float4 r;
            r.x = acc[i][0] + bv[i]; r.y = acc[i][1] + bv[i];
            r.z = acc[i][2] + bv[i]; r.w = acc[i][3] + bv[i];
            if (RELU) { r.x = fmaxf(r.x, 0.f); r.y = fmaxf(r.y, 0.f);
                        r.z = fmaxf(r.z, 0.f); r.w = fmaxf(r.w, 0.f); }
            *(float4*)&out[((size_t)(b * COUT + co)) * LOUT + l0 + 4 * ty] = r;
        }
    } else {
#pragma unroll
        for (int j = 0; j < 4; ++j) {
            const int l = l0 + 4 * ty + j;
            float4 r;
            r.x = acc[0][j] + bv[0]; r.y = acc[1][j] + bv[1];
            r.z = acc[2][j] + bv[2]; r.w = acc[3][j] + bv[3];
            if (RELU) { r.x = fmaxf(r.x, 0.f); r.y = fmaxf(r.y, 0.f);
                        r.z = fmaxf(r.z, 0.f); r.w = fmaxf(r.w, 0.f); }
            *(float4*)&out[((size_t)(b * LOUT + l)) * COUT + co0 + 4 * tx] = r;
        }
    }
}

// ---------------- row sum of squares (rows of length 512) ----------------
__global__ void rowsq_kernel(const float* __restrict__ src, float* __restrict__ dst) {
    const int r = blockIdx.x;
    const int lane = threadIdx.x;  // 64
    const float* row = src + (size_t)r * 512;
    float4 a = *(const float4*)&row[lane * 8];
    float4 c = *(const float4*)&row[lane * 8 + 4];
    float s = a.x * a.x + a.y * a.y + a.z * a.z + a.w * a.w
            + c.x * c.x + c.y * c.y + c.z * c.z + c.w * c.w;
#pragma unroll
    for (int off = 32; off > 0; off >>= 1) s += __shfl_down(s, off, 64);
    if (lane == 0) dst[r] = s;
}

// ---------------- fused cross-GEMM + argmin ----------------
// per (b,k): feats[b] (4096x512) x codebook[k]^T (512x2048), fused running argmin.
// block: 128 l x (loop over v in tiles of 128), 256 threads, 8x8 micro-tile.
__global__ __launch_bounds__(256) void cross_argmin_kernel(
    const float* __restrict__ feats, const float* __restrict__ cb,
    const float* __restrict__ f2, const float* __restrict__ c2,
    int* __restrict__ tokens_i, float* __restrict__ tokens_f) {
    __shared__ float smem[2 * 16 * 132];
    float* As = smem;               // [16][132] : A[kk][l]
    float* Bs = smem + 16 * 132;    // [16][132] : B[kk][v]
    const int tid = threadIdx.x;
    const int tx = tid & 15;   // v group
    const int ty = tid >> 4;   // l group
    const int l0 = blockIdx.x * 128;
    const int k  = blockIdx.y;
    const int b  = blockIdx.z;
    const float* A  = feats + ((size_t)b * L3V + l0) * 512;
    const float* Bm = cb + (size_t)k * VOCABV * 512;

    float f2v[8];
#pragma unroll
    for (int j = 0; j < 8; ++j) f2v[j] = f2[b * L3V + l0 + 8 * ty + j];

    float minv[8];
    int   mini[8];
#pragma unroll
    for (int j = 0; j < 8; ++j) { minv[j] = 3.4e38f; mini[j] = 0; }

    for (int vt = 0; vt < VOCABV; vt += 128) {
        float acc[8][8];  // [j=l][i=v]
#pragma unroll
        for (int j = 0; j < 8; ++j)
#pragma unroll
            for (int i = 0; i < 8; ++i) acc[j][i] = 0.f;

        for (int h0 = 0; h0 < 512; h0 += 16) {
            __syncthreads();
            for (int n = tid; n < 2048; n += 256) {
                int kk = n & 15;
                int l  = n >> 4;
                As[kk * 132 + l] = A[(size_t)l * 512 + h0 + kk];
                Bs[kk * 132 + l] = Bm[(size_t)(vt + l) * 512 + h0 + kk];
            }
            __syncthreads();
#pragma unroll
            for (int kk = 0; kk < 16; ++kk) {
                const float4 a0 = *(const float4*)&As[kk * 132 + 8 * ty];
                const float4 a1 = *(const float4*)&As[kk * 132 + 8 * ty + 4];
                const float4 b0 = *(const float4*)&Bs[kk * 132 + 8 * tx];
                const float4 b1 = *(const float4*)&Bs[kk * 132 + 8 * tx + 4];
                const float av[8] = {a0.x, a0.y, a0.z, a0.w, a1.x, a1.y, a1.z, a1.w};
                const float bv[8] = {b0.x, b0.y, b0.z, b0.w, b1.x, b1.y, b1.z, b1.w};
#pragma unroll
                for (int j = 0; j < 8; ++j)
#pragma unroll
                    for (int i = 0; i < 8; ++i)
                        acc[j][i] = fmaf(av[j], bv[i], acc[j][i]);
            }
        }
        // argmin update (v ascending for first-index tie-break)
        float c2v[8];
#pragma unroll
        for (int i = 0; i < 8; ++i) c2v[i] = c2[k * VOCABV + vt + 8 * tx + i];
#pragma unroll
        for (int j = 0; j < 8; ++j) {
#pragma unroll
            for (int i = 0; i < 8; ++i) {
                float d = (f2v[j] + c2v[i]) - 2.f * acc[j][i];
                if (d < minv[j]) { minv[j] = d; mini[j] = vt + 8 * tx + i; }
            }
        }
    }

    // cross-thread reduce over tx (16 candidates per l)
    __syncthreads();
    float* redv = smem;               // [128][16]
    int*   redi = (int*)(smem + 2048);
#pragma unroll
    for (int j = 0; j < 8; ++j) {
        redv[(8 * ty + j) * 16 + tx] = minv[j];
        redi[(8 * ty + j) * 16 + tx] = mini[j];
    }
    __syncthreads();
    if (tid < 128) {
        const int l = tid;
        float bestv = redv[l * 16 + 0];
        int   besti = redi[l * 16 + 0];
#pragma unroll
        for (int t = 1; t < 16; ++t) {
            float v = redv[l * 16 + t];
            int   iv = redi[l * 16 + t];
            if (v < bestv || (v == bestv && iv < besti)) { bestv = v; besti = iv; }
        }
        size_t o = ((size_t)(b * KCB + k)) * L3V + l0 + l;
        tokens_i[o] = besti;
        tokens_f[o] = (float)besti;
    }
}

// ---------------- embedding mean over 4 codebooks ----------------
__global__ void emb_kernel(const int* __restrict__ tokens, const float* __restrict__ E,
                           float* __restrict__ out) {
    const int l = blockIdx.x;
    const int b = blockIdx.y;
    const int h4 = threadIdx.x * 4;  // 128 threads
    const int t0 = tokens[((size_t)(b * KCB + 0)) * L3V + l];
    const int t1 = tokens[((size_t)(b * KCB + 1)) * L3V + l];
    const int t2 = tokens[((size_t)(b * KCB + 2)) * L3V + l];
    const int t3 = tokens[((size_t)(b * KCB + 3)) * L3V + l];
    const float4 e0 = *(const float4*)&E[(size_t)t0 * 512 + h4];
    const float4 e1 = *(const float4*)&E[(size_t)t1 * 512 + h4];
    const float4 e2 = *(const float4*)&E[(size_t)t2 * 512 + h4];
    const float4 e3 = *(const float4*)&E[(size_t)t3 * 512 + h4];
    float4 r;
    r.x = (e0.x + e1.x + e2.x + e3.x) * 0.25f;
    r.y = (e0.y + e1.y + e2.y + e3.y) * 0.25f;
    r.z = (e0.z + e1.z + e2.z + e3.z) * 0.25f;
    r.w = (e0.w + e1.w + e2.w + e3.w) * 0.25f;
    *(float4*)&out[((size_t)b * L3V + l) * 512 + h4] = r;
}

extern "C" void kernel_launch(void* const* d_in, const int* in_sizes, int n_in,
                              void* d_out, int out_size, void* d_ws, size_t ws_size,
                              hipStream_t stream) {
    const float* audio = (const float*)d_in[0];
    const float* w1 = (const float*)d_in[1];
    const float* b1 = (const float*)d_in[2];
    const float* w2 = (const float*)d_in[3];
    const float* b2 = (const float*)d_in[4];
    const float* w3 = (const float*)d_in[5];
    const float* b3 = (const float*)d_in[6];
    const float* cb = (const float*)d_in[7];
    const float* E  = (const float*)d_in[8];

    float* out_tok = (float*)d_out;
    float* out_emb = out_tok + (size_t)B_ * KCB * L3V;

    float* ws = (float*)d_ws;
    size_t off = 0;
    float* x1  = ws + off; off += (size_t)B_ * C1V * L1V;  // 8388608 (reused as feats)
    float* x2  = ws + off; off += (size_t)B_ * C2V * L2V;  // 8388608
    float* w2t = ws + off; off += (size_t)C1V * 7 * C2V;   // 229376
    float* w3t = ws + off; off += (size_t)C2V * 7 * C3V;   // 917504
    float* f2  = ws + off; off += (size_t)B_ * L3V;        // 16384
    float* c2  = ws + off; off += (size_t)KCB * VOCABV;    // 8192
    int*   tok = (int*)(ws + off);                          // 65536 ints
    float* feats = x1;

    transpose_w_kernel<<<(C1V * 7 * C2V + 255) / 256, 256, 0, stream>>>(w2, w2t, C1V, C2V);
    transpose_w_kernel<<<(C2V * 7 * C3V + 255) / 256, 256, 0, stream>>>(w3, w3t, C2V, C3V);

    conv1_kernel<<<dim3(L1V / 256, C1V, B_), 256, 0, stream>>>(audio, w1, b1, x1);

    conv_tiled_kernel<C1V, C2V, L1V, true, false>
        <<<dim3(L2V / 64, C2V / 64, B_), 256, 0, stream>>>(x1, w2t, b2, x2);

    conv_tiled_kernel<C2V, C3V, L2V, false, true>
        <<<dim3(L3V / 64, C3V / 64, B_), 256, 0, stream>>>(x2, w3t, b3, feats);

    rowsq_kernel<<<B_ * L3V, 64, 0, stream>>>(feats, f2);
    rowsq_kernel<<<KCB * VOCABV, 64, 0, stream>>>(cb, c2);

    cross_argmin_kernel<<<dim3(L3V / 128, KCB, B_), 256, 0, stream>>>(
        feats, cb, f2, c2, tok, out_tok);

    emb_kernel<<<dim3(L3V, B_), 128, 0, stream>>>(tok, E, out_emb);
}

// Round 2
// 1398.433 us; speedup vs baseline: 2.1494x; 2.1494x over previous
//
#include <hip/hip_runtime.h>
#include <hip/hip_bf16.h>

#define B_ 4
#define S_IN 32768
#define C1V 128
#define L1V 16384
#define C2V 256
#define L2V 8192
#define C3V 512
#define L3V 4096
#define VOCABV 2048
#define KCB 4

typedef _Float16 half8 __attribute__((ext_vector_type(8)));
typedef _Float16 half4v __attribute__((ext_vector_type(4)));
typedef float floatx4 __attribute__((ext_vector_type(4)));

#define AS1 __attribute__((address_space(1)))
#define AS3 __attribute__((address_space(3)))

__device__ __forceinline__ void gload_lds16(const void* g, void* l) {
    __builtin_amdgcn_global_load_lds((const AS1 void*)g, (AS3 void*)l, 16, 0, 0);
}

// ---------------- conv1: [B,1,S] -> [B,128,16384], k=7 s=2 p=3, relu ----------------
__global__ void conv1_kernel(const float* __restrict__ x, const float* __restrict__ w,
                             const float* __restrict__ bias, float* __restrict__ out) {
    __shared__ float xs[2 * 256 + 6];
    __shared__ float ws[7];
    const int l0 = blockIdx.x * 256;
    const int co = blockIdx.y;
    const int b  = blockIdx.z;
    const int tid = threadIdx.x;
    const float* xb = x + (size_t)b * S_IN;
    for (int n = tid; n < 2 * 256 + 6; n += 256) {
        int p = 2 * l0 - 3 + n;
        xs[n] = (p >= 0 && p < S_IN) ? xb[p] : 0.f;
    }
    if (tid < 7) ws[tid] = w[co * 7 + tid];
    __syncthreads();
    float acc = bias[co];
    const int base = 2 * tid;
#pragma unroll
    for (int t = 0; t < 7; ++t) acc = fmaf(ws[t], xs[base + t], acc);
    acc = fmaxf(acc, 0.f);
    out[((size_t)(b * C1V + co)) * L1V + l0 + tid] = acc;
}

// ---------------- weight transpose: w[co][ci][t] -> wt[ci][t][co] ----------------
__global__ void transpose_w_kernel(const float* __restrict__ w, float* __restrict__ wt,
                                   int cin, int cout) {
    int n = blockIdx.x * blockDim.x + threadIdx.x;
    int total = cin * 7 * cout;
    if (n >= total) return;
    int co = n % cout;
    int t  = (n / cout) % 7;
    int ci = n / (cout * 7);
    wt[n] = w[(co * cin + ci) * 7 + t];
}

// ---------------- tiled conv (k=7, s=2, p=3): implicit GEMM ----------------
template <int CIN, int COUT, int LIN, bool RELU, bool TRANS>
__global__ __launch_bounds__(256) void conv_tiled_kernel(
    const float* __restrict__ in, const float* __restrict__ wt,
    const float* __restrict__ bias, float* __restrict__ out) {
    constexpr int LOUT = LIN / 2;
    __shared__ float xs[2][16][68];
    const int tid = threadIdx.x;
    const int tx = tid & 15;   // co group
    const int ty = tid >> 4;   // l group
    const int l0  = blockIdx.x * 64;
    const int co0 = blockIdx.y * 64;
    const int b   = blockIdx.z;
    const float* inb = in + (size_t)b * CIN * LIN;

    float acc[4][4];  // [i=co][j=l]
#pragma unroll
    for (int i = 0; i < 4; ++i)
#pragma unroll
        for (int j = 0; j < 4; ++j) acc[i][j] = 0.f;

    for (int c0 = 0; c0 < CIN; c0 += 16) {
        __syncthreads();
        for (int n = tid; n < 2 * 16 * 68; n += 256) {
            int q   = n % 68;
            int rc  = n / 68;
            int ci  = rc & 15;
            int par = rc >> 4;
            int p = 2 * l0 + 2 * q + par - 3;
            float v = (p >= 0 && p < LIN) ? inb[(size_t)(c0 + ci) * LIN + p] : 0.f;
            xs[par][ci][q] = v;
        }
        __syncthreads();
#pragma unroll 2
        for (int ci = 0; ci < 16; ++ci) {
            const float4 e0 = *(const float4*)&xs[0][ci][4 * ty];
            const float4 e1 = *(const float4*)&xs[0][ci][4 * ty + 4];
            const float4 o0 = *(const float4*)&xs[1][ci][4 * ty];
            const float4 o1 = *(const float4*)&xs[1][ci][4 * ty + 4];
            const float xe[8] = {e0.x, e0.y, e0.z, e0.w, e1.x, e1.y, e1.z, e1.w};
            const float xo[8] = {o0.x, o0.y, o0.z, o0.w, o1.x, o1.y, o1.z, o1.w};
#pragma unroll
            for (int t = 0; t < 7; ++t) {
                const float* xx = (t & 1) ? xo : xe;
                const int t2 = t >> 1;
                const float4 w4 = *(const float4*)&wt[((size_t)(c0 + ci) * 7 + t) * COUT + co0 + 4 * tx];
                const float wv[4] = {w4.x, w4.y, w4.z, w4.w};
#pragma unroll
                for (int i = 0; i < 4; ++i)
#pragma unroll
                    for (int j = 0; j < 4; ++j)
                        acc[i][j] = fmaf(wv[i], xx[t2 + j], acc[i][j]);
            }
        }
    }
    float bv[4];
#pragma unroll
    for (int i = 0; i < 4; ++i) bv[i] = bias[co0 + 4 * tx + i];
    if (!TRANS) {
#pragma unroll
        for (int i = 0; i < 4; ++i) {
            const int co = co0 + 4 * tx + i;
            float4 r;
            r.x = acc[i][0] + bv[i]; r.y = acc[i][1] + bv[i];
            r.z = acc[i][2] + bv[i]; r.w = acc[i][3] + bv[i];
            if (RELU) { r.x = fmaxf(r.x, 0.f); r.y = fmaxf(r.y, 0.f);
                        r.z = fmaxf(r.z, 0.f); r.w = fmaxf(r.w, 0.f); }
            *(float4*)&out[((size_t)(b * COUT + co)) * LOUT + l0 + 4 * ty] = r;
        }
    } else {
#pragma unroll
        for (int j = 0; j < 4; ++j) {
            const int l = l0 + 4 * ty + j;
            float4 r;
            r.x = acc[0][j] + bv[0]; r.y = acc[1][j] + bv[1];
            r.z = acc[2][j] + bv[2]; r.w = acc[3][j] + bv[3];
            if (RELU) { r.x = fmaxf(r.x, 0.f); r.y = fmaxf(r.y, 0.f);
                        r.z = fmaxf(r.z, 0.f); r.w = fmaxf(r.w, 0.f); }
            *(float4*)&out[((size_t)(b * LOUT + l)) * COUT + co0 + 4 * tx] = r;
        }
    }
}

// ---------------- row sum of squares * 2^19 (codebook) ----------------
__global__ void rowsq_scale_kernel(const float* __restrict__ src, float* __restrict__ dst) {
    const int r = blockIdx.x;
    const int lane = threadIdx.x;  // 64
    const float* row = src + (size_t)r * 512;
    float4 a = *(const float4*)&row[lane * 8];
    float4 c = *(const float4*)&row[lane * 8 + 4];
    float s = a.x * a.x + a.y * a.y + a.z * a.z + a.w * a.w
            + c.x * c.x + c.y * c.y + c.z * c.z + c.w * c.w;
#pragma unroll
    for (int off = 32; off > 0; off >>= 1) s += __shfl_down(s, off, 64);
    if (lane == 0) dst[r] = s * 524288.f;  // 2^19: key = c2*2^19 - acc (acc = 2^20*cross)
}

// ---------------- fp32 -> scaled f16 hi/lo split: x[r][512] -> y[r][0:512]=hi(1024x), [512:1024]=lo
__global__ void split_f16_kernel(const float* __restrict__ x, _Float16* __restrict__ y) {
    const int r = blockIdx.x;
    const int t = threadIdx.x;  // 128 threads x 4 elems
    const float4 v = *(const float4*)(x + (size_t)r * 512 + t * 4);
    float a0 = v.x * 1024.f, a1 = v.y * 1024.f, a2 = v.z * 1024.f, a3 = v.w * 1024.f;
    _Float16 h0 = (_Float16)a0, h1 = (_Float16)a1, h2 = (_Float16)a2, h3 = (_Float16)a3;
    _Float16 l0 = (_Float16)(a0 - (float)h0), l1 = (_Float16)(a1 - (float)h1);
    _Float16 l2 = (_Float16)(a2 - (float)h2), l3 = (_Float16)(a3 - (float)h3);
    half4v hv = {h0, h1, h2, h3};
    half4v lv = {l0, l1, l2, l3};
    *(half4v*)(y + (size_t)r * 1024 + t * 4) = hv;
    *(half4v*)(y + (size_t)r * 1024 + 512 + t * 4) = lv;
}

// ---------------- MFMA cross-GEMM + fused argmin ----------------
// A' = [A_hi | A_lo], B' = [B_hi | B_lo], K'=1024 halfs per row.
// acc = A_hi*B_hi + A_lo*B_hi + A_hi*B_lo  (3-phase K loop) = 2^20 * cross (+eps)
// key = acc - c2*2^19 maximized <=> d2 minimized. Grid: (64 = 32 l-tiles x 2 v-halves, K, B).
__global__ __launch_bounds__(256, 3) void cross_mfma_kernel(
    const _Float16* __restrict__ Af, const _Float16* __restrict__ Bf,
    const float* __restrict__ c2p,
    float* __restrict__ candv, int* __restrict__ candi) {

    __shared__ _Float16 As[4096];   // [128 rows][32 k] contiguous, 64B rows
    __shared__ _Float16 Bs[4096];

    const int tid  = threadIdx.x;
    const int wave = tid >> 6;
    const int lane = tid & 63;
    const int wm = wave >> 1, wn = wave & 1;
    const int q  = lane >> 4;      // 0..3
    const int cl = lane & 15;

    const int lt = blockIdx.x >> 1;
    const int vh = blockIdx.x & 1;
    const int l0 = lt * 128;
    const int k  = blockIdx.y;
    const int b  = blockIdx.z;

    const _Float16* Ab = Af + (size_t)(b * L3V + l0) * 1024;
    const _Float16* Bb = Bf + ((size_t)k * VOCABV + vh * 1024) * 1024;

    const int ca   = (wave << 6) | lane;  // staging chunk 0..255
    const int rowA = ca >> 2;
    const int seg  = ca & 3;

    char* AsB = (char*)As;
    char* BsB = (char*)Bs;
    char* ldsA0 = AsB + wave * 1024;
    char* ldsA1 = AsB + 4096 + wave * 1024;
    char* ldsB0 = BsB + wave * 1024;
    char* ldsB1 = BsB + 4096 + wave * 1024;

    float maxv[4][4];
    int   maxi[4][4];
#pragma unroll
    for (int a = 0; a < 4; ++a)
#pragma unroll
        for (int r = 0; r < 4; ++r) { maxv[a][r] = -3.4e38f; maxi[a][r] = 0; }

    for (int vt = 0; vt < 8; ++vt) {
        const _Float16* Bt = Bb + (size_t)(vt * 128) * 1024;
        floatx4 acc[4][4];
#pragma unroll
        for (int a = 0; a < 4; ++a)
#pragma unroll
            for (int n = 0; n < 4; ++n) acc[a][n] = (floatx4){0.f, 0.f, 0.f, 0.f};

#pragma unroll 1
        for (int p = 0; p < 3; ++p) {
            const int ao = (p == 1) ? 512 : 0;
            const int bo = (p == 2) ? 512 : 0;
#pragma unroll 1
            for (int ko = 0; ko < 512; ko += 32) {
                __syncthreads();
                const _Float16* ga = Ab + (size_t)rowA * 1024 + ao + ko + seg * 8;
                const _Float16* gb = Bt + (size_t)rowA * 1024 + bo + ko + seg * 8;
                gload_lds16(ga, ldsA0);
                gload_lds16(ga + 64 * 1024, ldsA1);
                gload_lds16(gb, ldsB0);
                gload_lds16(gb + 64 * 1024, ldsB1);
                asm volatile("s_waitcnt vmcnt(0)" ::: "memory");
                __syncthreads();

                half8 af[4], bfr[4];
#pragma unroll
                for (int a = 0; a < 4; ++a)
                    af[a] = *(const half8*)&As[(wm * 64 + a * 16 + cl) * 32 + q * 8];
#pragma unroll
                for (int n = 0; n < 4; ++n)
                    bfr[n] = *(const half8*)&Bs[(wn * 64 + n * 16 + cl) * 32 + q * 8];
#pragma unroll
                for (int a = 0; a < 4; ++a)
#pragma unroll
                    for (int n = 0; n < 4; ++n)
                        acc[a][n] = __builtin_amdgcn_mfma_f32_16x16x32_f16(
                            af[a], bfr[n], acc[a][n], 0, 0, 0);
            }
        }

        // argmax(acc - c2*2^19) epilogue; ascending v order for tie-break
        const int vbase = vh * 1024 + vt * 128 + wn * 64 + cl;
        float c2v[4];
#pragma unroll
        for (int n = 0; n < 4; ++n) c2v[n] = c2p[k * VOCABV + vbase + n * 16];
#pragma unroll
        for (int a = 0; a < 4; ++a)
#pragma unroll
            for (int n = 0; n < 4; ++n) {
                const int vidx = vbase + n * 16;
#pragma unroll
                for (int r = 0; r < 4; ++r) {
                    float m = acc[a][n][r] - c2v[n];
                    if (m > maxv[a][r]) { maxv[a][r] = m; maxi[a][r] = vidx; }
                }
            }
    }

    // cross-lane reduce within 16-lane segments (same C-row)
#pragma unroll
    for (int a = 0; a < 4; ++a)
#pragma unroll
        for (int r = 0; r < 4; ++r) {
            float v = maxv[a][r]; int idx = maxi[a][r];
#pragma unroll
            for (int m = 1; m < 16; m <<= 1) {
                float ov = __shfl_xor(v, m, 64);
                int   oi = __shfl_xor(idx, m, 64);
                if (ov > v || (ov == v && oi < idx)) { v = ov; idx = oi; }
            }
            maxv[a][r] = v; maxi[a][r] = idx;
        }

    __syncthreads();
    float* redv = (float*)As;   // [128][2]
    int*   redi = (int*)Bs;
    if (cl == 0) {
#pragma unroll
        for (int a = 0; a < 4; ++a)
#pragma unroll
            for (int r = 0; r < 4; ++r) {
                int row = wm * 64 + a * 16 + q * 4 + r;
                redv[row * 2 + wn] = maxv[a][r];
                redi[row * 2 + wn] = maxi[a][r];
            }
    }
    __syncthreads();
    if (tid < 128) {
        float v0 = redv[tid * 2], v1 = redv[tid * 2 + 1];
        int   i0 = redi[tid * 2], i1 = redi[tid * 2 + 1];
        bool t1 = (v1 > v0) || (v1 == v0 && i1 < i0);
        float bv = t1 ? v1 : v0;
        int   bi = t1 ? i1 : i0;
        size_t o = (size_t)vh * (B_ * KCB * L3V) + ((size_t)(b * KCB + k)) * L3V + l0 + tid;
        candv[o] = bv;
        candi[o] = bi;
    }
}

// ---------------- merge the two v-halves ----------------
__global__ void merge_kernel(const float* __restrict__ cv, const int* __restrict__ ci,
                             int* __restrict__ ti, float* __restrict__ tf) {
    const int n = blockIdx.x * 256 + threadIdx.x;  // 65536
    float v0 = cv[n], v1 = cv[B_ * KCB * L3V + n];
    int   i0 = ci[n], i1 = ci[B_ * KCB * L3V + n];
    bool t1 = (v1 > v0);  // half1 indices always larger, so ties keep half0
    int best = t1 ? i1 : i0;
    ti[n] = best;
    tf[n] = (float)best;
}

// ---------------- embedding mean over 4 codebooks ----------------
__global__ void emb_kernel(const int* __restrict__ tokens, const float* __restrict__ E,
                           float* __restrict__ out) {
    const int l = blockIdx.x;
    const int b = blockIdx.y;
    const int h4 = threadIdx.x * 4;  // 128 threads
    const int t0 = tokens[((size_t)(b * KCB + 0)) * L3V + l];
    const int t1 = tokens[((size_t)(b * KCB + 1)) * L3V + l];
    const int t2 = tokens[((size_t)(b * KCB + 2)) * L3V + l];
    const int t3 = tokens[((size_t)(b * KCB + 3)) * L3V + l];
    const float4 e0 = *(const float4*)&E[(size_t)t0 * 512 + h4];
    const float4 e1 = *(const float4*)&E[(size_t)t1 * 512 + h4];
    const float4 e2 = *(const float4*)&E[(size_t)t2 * 512 + h4];
    const float4 e3 = *(const float4*)&E[(size_t)t3 * 512 + h4];
    float4 r;
    r.x = (e0.x + e1.x + e2.x + e3.x) * 0.25f;
    r.y = (e0.y + e1.y + e2.y + e3.y) * 0.25f;
    r.z = (e0.z + e1.z + e2.z + e3.z) * 0.25f;
    r.w = (e0.w + e1.w + e2.w + e3.w) * 0.25f;
    *(float4*)&out[((size_t)b * L3V + l) * 512 + h4] = r;
}

extern "C" void kernel_launch(void* const* d_in, const int* in_sizes, int n_in,
                              void* d_out, int out_size, void* d_ws, size_t ws_size,
                              hipStream_t stream) {
    const float* audio = (const float*)d_in[0];
    const float* w1 = (const float*)d_in[1];
    const float* b1 = (const float*)d_in[2];
    const float* w2 = (const float*)d_in[3];
    const float* b2 = (const float*)d_in[4];
    const float* w3 = (const float*)d_in[5];
    const float* b3 = (const float*)d_in[6];
    const float* cb = (const float*)d_in[7];
    const float* E  = (const float*)d_in[8];

    float* out_tok = (float*)d_out;
    float* out_emb = out_tok + (size_t)B_ * KCB * L3V;

    float* ws = (float*)d_ws;
    size_t off = 0;
    float* x1  = ws + off; off += (size_t)B_ * C1V * L1V;   // 8388608 (conv1 out / feats / later Bf)
    float* x2  = ws + off; off += (size_t)B_ * C2V * L2V;   // 8388608 (conv2 out / later Af)
    float* w2t = ws + off; off += (size_t)C1V * 7 * C2V;    // 229376
    float* w3t = ws + off; off += (size_t)C2V * 7 * C3V;    // 917504
    float* c2p = ws + off; off += (size_t)KCB * VOCABV;     // 8192
    int*   tok = (int*)(ws + off); off += (size_t)B_ * KCB * L3V;  // 65536
    float* candv = ws + off; off += 2 * (size_t)B_ * KCB * L3V;    // 131072
    int*   candi = (int*)(ws + off); off += 2 * (size_t)B_ * KCB * L3V;

    _Float16* Afh = (_Float16*)x2;  // feats hi/lo: 16384 rows x 1024 halfs (fits x2 exactly)
    _Float16* Bfh = (_Float16*)x1;  // codebook hi/lo: 8192 rows x 1024 halfs (fits x1)

    transpose_w_kernel<<<(C1V * 7 * C2V + 255) / 256, 256, 0, stream>>>(w2, w2t, C1V, C2V);
    transpose_w_kernel<<<(C2V * 7 * C3V + 255) / 256, 256, 0, stream>>>(w3, w3t, C2V, C3V);

    conv1_kernel<<<dim3(L1V / 256, C1V, B_), 256, 0, stream>>>(audio, w1, b1, x1);

    conv_tiled_kernel<C1V, C2V, L1V, true, false>
        <<<dim3(L2V / 64, C2V / 64, B_), 256, 0, stream>>>(x1, w2t, b2, x2);

    conv_tiled_kernel<C2V, C3V, L2V, false, true>
        <<<dim3(L3V / 64, C3V / 64, B_), 256, 0, stream>>>(x2, w3t, b3, x1 /*feats [B][L][512]*/);

    rowsq_scale_kernel<<<KCB * VOCABV, 64, 0, stream>>>(cb, c2p);

    split_f16_kernel<<<B_ * L3V, 128, 0, stream>>>(x1, Afh);   // feats -> Af (x2 region)
    split_f16_kernel<<<KCB * VOCABV, 128, 0, stream>>>(cb, Bfh);  // cb -> Bf (x1 region)

    cross_mfma_kernel<<<dim3(64, KCB, B_), 256, 0, stream>>>(Afh, Bfh, c2p, candv, candi);

    merge_kernel<<<(B_ * KCB * L3V) / 256, 256, 0, stream>>>(candv, candi, tok, out_tok);

    emb_kernel<<<dim3(L3V, B_), 128, 0, stream>>>(tok, E, out_emb);
}

// Round 3
// 1127.692 us; speedup vs baseline: 2.6655x; 1.2401x over previous
//
#include <hip/hip_runtime.h>
#include <hip/hip_bf16.h>

#define B_ 4
#define S_IN 32768
#define C1V 128
#define L1V 16384
#define C2V 256
#define L2V 8192
#define C3V 512
#define L3V 4096
#define VOCABV 2048
#define KCB 4

typedef _Float16 half8 __attribute__((ext_vector_type(8)));
typedef float floatx4 __attribute__((ext_vector_type(4)));

#define AS1 __attribute__((address_space(1)))
#define AS3 __attribute__((address_space(3)))

__device__ __forceinline__ void gload_lds16(const void* g, void* l) {
    __builtin_amdgcn_global_load_lds((const AS1 void*)g, (AS3 void*)l, 16, 0, 0);
}

// ---------------- conv1: [B,1,S] -> [B,128,16384], k=7 s=2 p=3, relu ----------------
__global__ void conv1_kernel(const float* __restrict__ x, const float* __restrict__ w,
                             const float* __restrict__ bias, float* __restrict__ out) {
    __shared__ float xs[2 * 256 + 6];
    __shared__ float ws[7];
    const int l0 = blockIdx.x * 256;
    const int co = blockIdx.y;
    const int b  = blockIdx.z;
    const int tid = threadIdx.x;
    const float* xb = x + (size_t)b * S_IN;
    for (int n = tid; n < 2 * 256 + 6; n += 256) {
        int p = 2 * l0 - 3 + n;
        xs[n] = (p >= 0 && p < S_IN) ? xb[p] : 0.f;
    }
    if (tid < 7) ws[tid] = w[co * 7 + tid];
    __syncthreads();
    float acc = bias[co];
    const int base = 2 * tid;
#pragma unroll
    for (int t = 0; t < 7; ++t) acc = fmaf(ws[t], xs[base + t], acc);
    acc = fmaxf(acc, 0.f);
    out[((size_t)(b * C1V + co)) * L1V + l0 + tid] = acc;
}

// ---------------- weight transpose: w[co][ci][t] -> wt[ci][t][co] ----------------
__global__ void transpose_w_kernel(const float* __restrict__ w, float* __restrict__ wt,
                                   int cin, int cout) {
    int n = blockIdx.x * blockDim.x + threadIdx.x;
    int total = cin * 7 * cout;
    if (n >= total) return;
    int co = n % cout;
    int t  = (n / cout) % 7;
    int ci = n / (cout * 7);
    wt[n] = w[(co * cin + ci) * 7 + t];
}

// ---------------- conv implicit-GEMM v2: 128co x 128l tile, 8x8 micro ----------------
// OUTMODE 0: fp32 [B][co][LOUT] (+relu). OUTMODE 1: fused 1024x-scale f16 hi/lo split
// into outh[(b*LOUT+l)*1024 + {co | 512+co}] (feeds cross MFMA directly).
template <int CIN, int COUT, int LIN, bool RELU, int OUTMODE>
__global__ __launch_bounds__(256) void conv_gemm_kernel(
    const float* __restrict__ in, const float* __restrict__ wt,
    const float* __restrict__ bias, float* __restrict__ out,
    _Float16* __restrict__ outh) {
    constexpr int LOUT = LIN / 2;
    __shared__ float Xs[4][2][136];   // [ci][parity][j]: x[ci][2*(l0-2+j)+par]
    __shared__ float Ws[4 * 7 * 128]; // [ci*7+t][co 128]
    const int tid = threadIdx.x;
    const int txc = tid & 15;   // co/8
    const int txl = tid >> 4;   // l/8
    const int l0  = blockIdx.x * 128;
    const int co0 = blockIdx.y * 128;
    const int b   = blockIdx.z;
    const float* inb = in + (size_t)b * CIN * LIN;

    float acc[8][8];  // [i=co][j=l]
#pragma unroll
    for (int i = 0; i < 8; ++i)
#pragma unroll
        for (int j = 0; j < 8; ++j) acc[i][j] = 0.f;

    for (int c0 = 0; c0 < CIN; c0 += 4) {
        __syncthreads();
        // stage weights: rows r = ci*7+t (global row c0*7+r), 128 co slice
        for (int n = tid; n < 896; n += 256) {
            int r  = n >> 5;
            int c4 = (n & 31) * 4;
            *(float4*)&Ws[r * 128 + c4] =
                *(const float4*)&wt[((size_t)(c0 * 7 + r)) * COUT + co0 + c4];
        }
        // stage input, parity-split: 4 ci x 264 positions starting at 2*l0-4
        for (int n = tid; n < 4 * 264; n += 256) {
            int ci = n / 264;
            int m  = n - ci * 264;
            int p  = 2 * l0 - 4 + m;
            float v = (p >= 0 && p < LIN) ? inb[(size_t)(c0 + ci) * LIN + p] : 0.f;
            Xs[ci][m & 1][m >> 1] = v;
        }
        __syncthreads();
#pragma unroll
        for (int ci = 0; ci < 4; ++ci) {
            float xe[12], xo[12];
            *(float4*)&xe[0] = *(const float4*)&Xs[ci][0][8 * txl];
            *(float4*)&xe[4] = *(const float4*)&Xs[ci][0][8 * txl + 4];
            *(float4*)&xe[8] = *(const float4*)&Xs[ci][0][8 * txl + 8];
            *(float4*)&xo[0] = *(const float4*)&Xs[ci][1][8 * txl];
            *(float4*)&xo[4] = *(const float4*)&Xs[ci][1][8 * txl + 4];
            *(float4*)&xo[8] = *(const float4*)&Xs[ci][1][8 * txl + 8];
#pragma unroll
            for (int t = 0; t < 7; ++t) {
                const float* xx = ((t + 1) & 1) ? xo : xe;  // t even -> odd positions
                const int j0 = (t + 1) >> 1;
                const float4 w0 = *(const float4*)&Ws[(ci * 7 + t) * 128 + 8 * txc];
                const float4 w1 = *(const float4*)&Ws[(ci * 7 + t) * 128 + 8 * txc + 4];
                const float wv[8] = {w0.x, w0.y, w0.z, w0.w, w1.x, w1.y, w1.z, w1.w};
#pragma unroll
                for (int i = 0; i < 8; ++i)
#pragma unroll
                    for (int j = 0; j < 8; ++j)
                        acc[i][j] = fmaf(wv[i], xx[j0 + j], acc[i][j]);
            }
        }
    }

    float bv[8];
#pragma unroll
    for (int i = 0; i < 8; ++i) bv[i] = bias[co0 + 8 * txc + i];
    if (OUTMODE == 0) {
#pragma unroll
        for (int i = 0; i < 8; ++i) {
            const int co = co0 + 8 * txc + i;
            float r[8];
#pragma unroll
            for (int j = 0; j < 8; ++j) {
                r[j] = acc[i][j] + bv[i];
                if (RELU) r[j] = fmaxf(r[j], 0.f);
            }
            float* dst = &out[((size_t)(b * COUT + co)) * LOUT + l0 + 8 * txl];
            *(float4*)&dst[0] = *(float4*)&r[0];
            *(float4*)&dst[4] = *(float4*)&r[4];
        }
    } else {
#pragma unroll
        for (int j = 0; j < 8; ++j) {
            const int l = l0 + 8 * txl + j;
            half8 hv, lv;
#pragma unroll
            for (int i = 0; i < 8; ++i) {
                float a = (acc[i][j] + bv[i]) * 1024.f;
                _Float16 h = (_Float16)a;
                hv[i] = h;
                lv[i] = (_Float16)(a - (float)h);
            }
            _Float16* dst = outh + ((size_t)b * L3V + l) * 1024 + co0 + 8 * txc;
            *(half8*)dst = hv;
            *(half8*)(dst + 512) = lv;
        }
    }
}

// ---------------- row sum of squares * 2^19 (codebook) ----------------
__global__ void rowsq_scale_kernel(const float* __restrict__ src, float* __restrict__ dst) {
    const int r = blockIdx.x;
    const int lane = threadIdx.x;  // 64
    const float* row = src + (size_t)r * 512;
    float4 a = *(const float4*)&row[lane * 8];
    float4 c = *(const float4*)&row[lane * 8 + 4];
    float s = a.x * a.x + a.y * a.y + a.z * a.z + a.w * a.w
            + c.x * c.x + c.y * c.y + c.z * c.z + c.w * c.w;
#pragma unroll
    for (int off = 32; off > 0; off >>= 1) s += __shfl_down(s, off, 64);
    if (lane == 0) dst[r] = s * 524288.f;  // 2^19
}

// ---------------- fp32 -> scaled f16 hi/lo split (codebook) ----------------
__global__ void split_f16_kernel(const float* __restrict__ x, _Float16* __restrict__ y) {
    const int r = blockIdx.x;
    const int t = threadIdx.x;  // 128 threads x 4 elems
    const float4 v = *(const float4*)(x + (size_t)r * 512 + t * 4);
    float a0 = v.x * 1024.f, a1 = v.y * 1024.f, a2 = v.z * 1024.f, a3 = v.w * 1024.f;
    _Float16 h0 = (_Float16)a0, h1 = (_Float16)a1, h2 = (_Float16)a2, h3 = (_Float16)a3;
    typedef _Float16 half4v __attribute__((ext_vector_type(4)));
    half4v hv = {h0, h1, h2, h3};
    half4v lv = {(_Float16)(a0 - (float)h0), (_Float16)(a1 - (float)h1),
                 (_Float16)(a2 - (float)h2), (_Float16)(a3 - (float)h3)};
    *(half4v*)(y + (size_t)r * 1024 + t * 4) = hv;
    *(half4v*)(y + (size_t)r * 1024 + 512 + t * 4) = lv;
}

// ---------------- MFMA cross-GEMM + fused argmin (flattened 3-product K loop) ----
// acc = Ahi*Bhi + Alo*Bhi + Ahi*Blo = 2^20*cross (+eps); key = acc - c2*2^19.
// Per ko chunk: stage Ahi/Alo/Bhi/Blo (4x8KB), 16 frag reads, 48 MFMAs.
__global__ __launch_bounds__(256, 3) void cross_mfma_kernel(
    const _Float16* __restrict__ Af, const _Float16* __restrict__ Bf,
    const float* __restrict__ c2p,
    float* __restrict__ candv, int* __restrict__ candi) {

    __shared__ _Float16 AsH[4096], AsL[4096], BsH[4096], BsL[4096];

    const int tid  = threadIdx.x;
    const int wave = tid >> 6;
    const int lane = tid & 63;
    const int wm = wave >> 1, wn = wave & 1;
    const int q  = lane >> 4;
    const int cl = lane & 15;

    const int lt = blockIdx.x >> 1;
    const int vh = blockIdx.x & 1;
    const int l0 = lt * 128;
    const int k  = blockIdx.y;
    const int b  = blockIdx.z;

    const _Float16* Ab = Af + (size_t)(b * L3V + l0) * 1024;
    const _Float16* Bb = Bf + ((size_t)k * VOCABV + vh * 1024) * 1024;

    const int rowA = tid >> 2;   // 0..63
    const int seg  = tid & 3;

    char* dAH0 = (char*)AsH + wave * 1024; char* dAH1 = dAH0 + 4096;
    char* dAL0 = (char*)AsL + wave * 1024; char* dAL1 = dAL0 + 4096;
    char* dBH0 = (char*)BsH + wave * 1024; char* dBH1 = dBH0 + 4096;
    char* dBL0 = (char*)BsL + wave * 1024; char* dBL1 = dBL0 + 4096;

    float maxv[4][4];
    int   maxi[4][4];
#pragma unroll
    for (int a = 0; a < 4; ++a)
#pragma unroll
        for (int r = 0; r < 4; ++r) { maxv[a][r] = -3.4e38f; maxi[a][r] = 0; }

    for (int vt = 0; vt < 8; ++vt) {
        const _Float16* Bt = Bb + (size_t)(vt * 128) * 1024;
        floatx4 acc[4][4];
#pragma unroll
        for (int a = 0; a < 4; ++a)
#pragma unroll
            for (int n = 0; n < 4; ++n) acc[a][n] = (floatx4){0.f, 0.f, 0.f, 0.f};

#pragma unroll 1
        for (int ko = 0; ko < 512; ko += 32) {
            __syncthreads();
            const _Float16* ga = Ab + (size_t)rowA * 1024 + ko + seg * 8;
            const _Float16* gb = Bt + (size_t)rowA * 1024 + ko + seg * 8;
            gload_lds16(ga,               dAH0);
            gload_lds16(ga + 64 * 1024,   dAH1);
            gload_lds16(ga + 512,         dAL0);
            gload_lds16(ga + 512 + 64 * 1024, dAL1);
            gload_lds16(gb,               dBH0);
            gload_lds16(gb + 64 * 1024,   dBH1);
            gload_lds16(gb + 512,         dBL0);
            gload_lds16(gb + 512 + 64 * 1024, dBL1);
            asm volatile("s_waitcnt vmcnt(0)" ::: "memory");
            __syncthreads();

            half8 afh[4], afl[4], bfh[4], bfl[4];
#pragma unroll
            for (int a = 0; a < 4; ++a) {
                const int ro = (wm * 64 + a * 16 + cl) * 32 + q * 8;
                afh[a] = *(const half8*)&AsH[ro];
                afl[a] = *(const half8*)&AsL[ro];
            }
#pragma unroll
            for (int n = 0; n < 4; ++n) {
                const int ro = (wn * 64 + n * 16 + cl) * 32 + q * 8;
                bfh[n] = *(const half8*)&BsH[ro];
                bfl[n] = *(const half8*)&BsL[ro];
            }
#pragma unroll
            for (int a = 0; a < 4; ++a)
#pragma unroll
                for (int n = 0; n < 4; ++n) {
                    acc[a][n] = __builtin_amdgcn_mfma_f32_16x16x32_f16(afh[a], bfh[n], acc[a][n], 0, 0, 0);
                    acc[a][n] = __builtin_amdgcn_mfma_f32_16x16x32_f16(afl[a], bfh[n], acc[a][n], 0, 0, 0);
                    acc[a][n] = __builtin_amdgcn_mfma_f32_16x16x32_f16(afh[a], bfl[n], acc[a][n], 0, 0, 0);
                }
        }

        const int vbase = vh * 1024 + vt * 128 + wn * 64 + cl;
        float c2v[4];
#pragma unroll
        for (int n = 0; n < 4; ++n) c2v[n] = c2p[k * VOCABV + vbase + n * 16];
#pragma unroll
        for (int a = 0; a < 4; ++a)
#pragma unroll
            for (int n = 0; n < 4; ++n) {
                const int vidx = vbase + n * 16;
#pragma unroll
                for (int r = 0; r < 4; ++r) {
                    float m = acc[a][n][r] - c2v[n];
                    if (m > maxv[a][r]) { maxv[a][r] = m; maxi[a][r] = vidx; }
                }
            }
    }

    // cross-lane reduce within 16-lane segments (same C-row)
#pragma unroll
    for (int a = 0; a < 4; ++a)
#pragma unroll
        for (int r = 0; r < 4; ++r) {
            float v = maxv[a][r]; int idx = maxi[a][r];
#pragma unroll
            for (int m = 1; m < 16; m <<= 1) {
                float ov = __shfl_xor(v, m, 64);
                int   oi = __shfl_xor(idx, m, 64);
                if (ov > v || (ov == v && oi < idx)) { v = ov; idx = oi; }
            }
            maxv[a][r] = v; maxi[a][r] = idx;
        }

    __syncthreads();
    float* redv = (float*)AsH;   // [128][2]
    int*   redi = (int*)BsH;
    if (cl == 0) {
#pragma unroll
        for (int a = 0; a < 4; ++a)
#pragma unroll
            for (int r = 0; r < 4; ++r) {
                int row = wm * 64 + a * 16 + q * 4 + r;
                redv[row * 2 + wn] = maxv[a][r];
                redi[row * 2 + wn] = maxi[a][r];
            }
    }
    __syncthreads();
    if (tid < 128) {
        float v0 = redv[tid * 2], v1 = redv[tid * 2 + 1];
        int   i0 = redi[tid * 2], i1 = redi[tid * 2 + 1];
        bool t1 = (v1 > v0) || (v1 == v0 && i1 < i0);
        float bv = t1 ? v1 : v0;
        int   bi = t1 ? i1 : i0;
        size_t o = (size_t)vh * (B_ * KCB * L3V) + ((size_t)(b * KCB + k)) * L3V + l0 + tid;
        candv[o] = bv;
        candi[o] = bi;
    }
}

// ---------------- merge the two v-halves ----------------
__global__ void merge_kernel(const float* __restrict__ cv, const int* __restrict__ ci,
                             int* __restrict__ ti, float* __restrict__ tf) {
    const int n = blockIdx.x * 256 + threadIdx.x;
    float v0 = cv[n], v1 = cv[B_ * KCB * L3V + n];
    int   i0 = ci[n], i1 = ci[B_ * KCB * L3V + n];
    bool t1 = (v1 > v0);  // half1 indices always larger: ties keep half0
    int best = t1 ? i1 : i0;
    ti[n] = best;
    tf[n] = (float)best;
}

// ---------------- embedding mean over 4 codebooks ----------------
__global__ void emb_kernel(const int* __restrict__ tokens, const float* __restrict__ E,
                           float* __restrict__ out) {
    const int l = blockIdx.x;
    const int b = blockIdx.y;
    const int h4 = threadIdx.x * 4;
    const int t0 = tokens[((size_t)(b * KCB + 0)) * L3V + l];
    const int t1 = tokens[((size_t)(b * KCB + 1)) * L3V + l];
    const int t2 = tokens[((size_t)(b * KCB + 2)) * L3V + l];
    const int t3 = tokens[((size_t)(b * KCB + 3)) * L3V + l];
    const float4 e0 = *(const float4*)&E[(size_t)t0 * 512 + h4];
    const float4 e1 = *(const float4*)&E[(size_t)t1 * 512 + h4];
    const float4 e2 = *(const float4*)&E[(size_t)t2 * 512 + h4];
    const float4 e3 = *(const float4*)&E[(size_t)t3 * 512 + h4];
    float4 r;
    r.x = (e0.x + e1.x + e2.x + e3.x) * 0.25f;
    r.y = (e0.y + e1.y + e2.y + e3.y) * 0.25f;
    r.z = (e0.z + e1.z + e2.z + e3.z) * 0.25f;
    r.w = (e0.w + e1.w + e2.w + e3.w) * 0.25f;
    *(float4*)&out[((size_t)b * L3V + l) * 512 + h4] = r;
}

extern "C" void kernel_launch(void* const* d_in, const int* in_sizes, int n_in,
                              void* d_out, int out_size, void* d_ws, size_t ws_size,
                              hipStream_t stream) {
    const float* audio = (const float*)d_in[0];
    const float* w1 = (const float*)d_in[1];
    const float* b1 = (const float*)d_in[2];
    const float* w2 = (const float*)d_in[3];
    const float* b2 = (const float*)d_in[4];
    const float* w3 = (const float*)d_in[5];
    const float* b3 = (const float*)d_in[6];
    const float* cb = (const float*)d_in[7];
    const float* E  = (const float*)d_in[8];

    float* out_tok = (float*)d_out;
    float* out_emb = out_tok + (size_t)B_ * KCB * L3V;

    float* ws = (float*)d_ws;
    size_t off = 0;
    float* x1  = ws + off; off += (size_t)B_ * C1V * L1V;   // 33.5MB: conv1 out, later Afh overlay
    float* x2f = ws + off; off += (size_t)B_ * C2V * L2V / 2 * 1; // conv2 out [B][256][4096] = 16.8MB
    off = ((size_t)B_ * C1V * L1V) + ((size_t)B_ * C2V * L2V / 2);
    float* bfh_f = ws + off; off += (size_t)KCB * VOCABV * 1024 / 2;  // Bfh 16.8MB (halfs/2 floats)
    float* w2t = ws + off; off += (size_t)C1V * 7 * C2V;
    float* w3t = ws + off; off += (size_t)C2V * 7 * C3V;
    float* c2p = ws + off; off += (size_t)KCB * VOCABV;
    int*   tok = (int*)(ws + off); off += (size_t)B_ * KCB * L3V;
    float* candv = ws + off; off += 2 * (size_t)B_ * KCB * L3V;
    int*   candi = (int*)(ws + off); off += 2 * (size_t)B_ * KCB * L3V;

    _Float16* Afh = (_Float16*)x1;     // conv3 writes here (x1 dead after conv2)
    _Float16* Bfh = (_Float16*)bfh_f;

    transpose_w_kernel<<<(C1V * 7 * C2V + 255) / 256, 256, 0, stream>>>(w2, w2t, C1V, C2V);
    transpose_w_kernel<<<(C2V * 7 * C3V + 255) / 256, 256, 0, stream>>>(w3, w3t, C2V, C3V);

    conv1_kernel<<<dim3(L1V / 256, C1V, B_), 256, 0, stream>>>(audio, w1, b1, x1);

    conv_gemm_kernel<C1V, C2V, L1V, true, 0>
        <<<dim3(L2V / 128, C2V / 128, B_), 256, 0, stream>>>(x1, w2t, b2, x2f, nullptr);

    conv_gemm_kernel<C2V, C3V, L2V, false, 1>
        <<<dim3(L3V / 128, C3V / 128, B_), 256, 0, stream>>>(x2f, w3t, b3, nullptr, Afh);

    rowsq_scale_kernel<<<KCB * VOCABV, 64, 0, stream>>>(cb, c2p);
    split_f16_kernel<<<KCB * VOCABV, 128, 0, stream>>>(cb, Bfh);

    cross_mfma_kernel<<<dim3(64, KCB, B_), 256, 0, stream>>>(Afh, Bfh, c2p, candv, candi);

    merge_kernel<<<(B_ * KCB * L3V) / 256, 256, 0, stream>>>(candv, candi, tok, out_tok);

    emb_kernel<<<dim3(L3V, B_), 128, 0, stream>>>(tok, E, out_emb);
}

// Round 4
// 813.054 us; speedup vs baseline: 3.6970x; 1.3870x over previous
//
#include <hip/hip_runtime.h>
#include <hip/hip_bf16.h>
#include <stdint.h>

#define B_ 4
#define S_IN 32768
#define C1V 128
#define L1V 16384
#define C2V 256
#define L2V 8192
#define C3V 512
#define L3V 4096
#define VOCABV 2048
#define KCB 4

typedef _Float16 half8 __attribute__((ext_vector_type(8)));
typedef float floatx4 __attribute__((ext_vector_type(4)));

#define AS1 __attribute__((address_space(1)))
#define AS3 __attribute__((address_space(3)))

__device__ __forceinline__ void gload_lds16(const void* g, void* l) {
    __builtin_amdgcn_global_load_lds((const AS1 void*)g, (AS3 void*)l, 16, 0, 0);
}

// read 8 halfs at a 4B-aligned LDS address (4x ds_read_b32)
__device__ __forceinline__ half8 lds_read_half8_a4(const _Float16* p) {
    union { uint32_t u[4]; half8 h; } t;
    const uint32_t* w = (const uint32_t*)p;
    t.u[0] = w[0]; t.u[1] = w[1]; t.u[2] = w[2]; t.u[3] = w[3];
    return t.h;
}

// ---------------- conv1: [B,1,S] -> [B,128,16384], k=7 s=2 p=3, relu ----------------
__global__ void conv1_kernel(const float* __restrict__ x, const float* __restrict__ w,
                             const float* __restrict__ bias, float* __restrict__ out) {
    __shared__ float xs[2 * 256 + 6];
    __shared__ float ws[7];
    const int l0 = blockIdx.x * 256;
    const int co = blockIdx.y;
    const int b  = blockIdx.z;
    const int tid = threadIdx.x;
    const float* xb = x + (size_t)b * S_IN;
    for (int n = tid; n < 2 * 256 + 6; n += 256) {
        int p = 2 * l0 - 3 + n;
        xs[n] = (p >= 0 && p < S_IN) ? xb[p] : 0.f;
    }
    if (tid < 7) ws[tid] = w[co * 7 + tid];
    __syncthreads();
    float acc = bias[co];
    const int base = 2 * tid;
#pragma unroll
    for (int t = 0; t < 7; ++t) acc = fmaf(ws[t], xs[base + t], acc);
    acc = fmaxf(acc, 0.f);
    out[((size_t)(b * C1V + co)) * L1V + l0 + tid] = acc;
}

// ---------------- weight prep: w[co][ci][7] fp32 -> hi/lo f16 planes [co][ci*8+u] ----
// u=0 dummy (zero), u=1..7 -> w[...][u-1] * 1024, hi/lo split.
__global__ void wsplit_kernel(const float* __restrict__ w, _Float16* __restrict__ wh,
                              _Float16* __restrict__ wl, int cin, int cout) {
    int idx = blockIdx.x * 256 + threadIdx.x;
    if (idx >= cin * cout) return;
    int co = idx / cin;
    int ci = idx - co * cin;
    const float* src = w + ((size_t)co * cin + ci) * 7;
    half8 h, l;
    h[0] = (_Float16)0.f; l[0] = (_Float16)0.f;
#pragma unroll
    for (int u = 1; u < 8; ++u) {
        float v = src[u - 1] * 1024.f;
        _Float16 hh = (_Float16)v;
        h[u] = hh;
        l[u] = (_Float16)(v - (float)hh);
    }
    size_t o = (size_t)co * (cin * 8) + ci * 8;
    *(half8*)(wh + o) = h;
    *(half8*)(wl + o) = l;
}

// ---------------- conv2 via f16 3-product MFMA: A=W (m=co), B=X windows (n=l) -------
// out fp32 [B][256][8192] with relu. K' = 128ci*8 = 1024, chunks of 32 (4 ci).
__global__ __launch_bounds__(256, 2) void conv2_mfma_kernel(
    const float* __restrict__ in, const _Float16* __restrict__ WH,
    const _Float16* __restrict__ WL, const float* __restrict__ bias,
    float* __restrict__ out) {
    __shared__ _Float16 XsH[4 * 272], XsL[4 * 272];
    __shared__ _Float16 WsH[128 * 32], WsL[128 * 32];
    const int tid = threadIdx.x;
    const int wave = tid >> 6;
    const int lane = tid & 63;
    const int wm = wave >> 1, wn = wave & 1;
    const int q  = lane >> 4;
    const int cl = lane & 15;
    const int l0  = blockIdx.x * 128;
    const int co0 = blockIdx.y * 128;
    const int b   = blockIdx.z;
    const float* inb = in + (size_t)b * C1V * L1V;

    floatx4 acc[4][4];
#pragma unroll
    for (int a = 0; a < 4; ++a)
#pragma unroll
        for (int n = 0; n < 4; ++n) acc[a][n] = (floatx4){0.f, 0.f, 0.f, 0.f};

    for (int ch = 0; ch < 32; ++ch) {
        __syncthreads();
        // stage X (4 ci rows, window [2l0-4, 2l0+259]), scaled x1024, hi/lo split
        for (int n = tid; n < 4 * 264; n += 256) {
            int ci = n / 264;
            int m  = n - ci * 264;
            int p  = 2 * l0 - 4 + m;
            float v = (p >= 0 && p < L1V) ? inb[(size_t)(ch * 4 + ci) * L1V + p] * 1024.f : 0.f;
            _Float16 h = (_Float16)v;
            XsH[ci * 272 + m] = h;
            XsL[ci * 272 + m] = (_Float16)(v - (float)h);
        }
        // stage W planes [co 128][k 32] via global_load_lds
        const int k0 = ch * 32;
        for (int g = wave; g < 8; g += 4) {
            const _Float16* gh = WH + (size_t)(co0 + g * 16 + (lane >> 2)) * 1024 + k0 + (lane & 3) * 8;
            const _Float16* gl = WL + (size_t)(co0 + g * 16 + (lane >> 2)) * 1024 + k0 + (lane & 3) * 8;
            gload_lds16(gh, (char*)WsH + g * 1024);
            gload_lds16(gl, (char*)WsL + g * 1024);
        }
        asm volatile("s_waitcnt vmcnt(0)" ::: "memory");
        __syncthreads();

        half8 awh[4], awl[4], bxh[4], bxl[4];
#pragma unroll
        for (int a = 0; a < 4; ++a) {
            const int ro = (wm * 64 + a * 16 + cl) * 32 + q * 8;
            awh[a] = *(const half8*)&WsH[ro];
            awl[a] = *(const half8*)&WsL[ro];
        }
#pragma unroll
        for (int n = 0; n < 4; ++n) {
            const int lrel = wn * 64 + n * 16 + cl;
            bxh[n] = lds_read_half8_a4(&XsH[q * 272 + 2 * lrel]);
            bxl[n] = lds_read_half8_a4(&XsL[q * 272 + 2 * lrel]);
        }
#pragma unroll
        for (int a = 0; a < 4; ++a)
#pragma unroll
            for (int n = 0; n < 4; ++n) {
                acc[a][n] = __builtin_amdgcn_mfma_f32_16x16x32_f16(awh[a], bxh[n], acc[a][n], 0, 0, 0);
                acc[a][n] = __builtin_amdgcn_mfma_f32_16x16x32_f16(awl[a], bxh[n], acc[a][n], 0, 0, 0);
                acc[a][n] = __builtin_amdgcn_mfma_f32_16x16x32_f16(awh[a], bxl[n], acc[a][n], 0, 0, 0);
            }
    }

    float bv[4][4];
#pragma unroll
    for (int a = 0; a < 4; ++a)
#pragma unroll
        for (int r = 0; r < 4; ++r) bv[a][r] = bias[co0 + wm * 64 + a * 16 + q * 4 + r];
#pragma unroll
    for (int a = 0; a < 4; ++a)
#pragma unroll
        for (int n = 0; n < 4; ++n) {
            const int l = l0 + wn * 64 + n * 16 + cl;
#pragma unroll
            for (int r = 0; r < 4; ++r) {
                const int co = co0 + wm * 64 + a * 16 + q * 4 + r;
                float vv = fmaxf(acc[a][n][r] * (1.f / 1048576.f) + bv[a][r], 0.f);
                out[((size_t)(b * C2V + co)) * L2V + l] = vv;
            }
        }
}

// ---------------- conv3 via f16 3-product MFMA: A=X windows (m=l), B=W (n=co) -------
// epilogue: fused x1024 hi/lo split into Afh[(b*L+l)*1024 + {co | 512+co}].
__global__ __launch_bounds__(256, 2) void conv3_mfma_kernel(
    const float* __restrict__ in, const _Float16* __restrict__ WH,
    const _Float16* __restrict__ WL, const float* __restrict__ bias,
    _Float16* __restrict__ outh) {
    __shared__ _Float16 XsH[4 * 272], XsL[4 * 272];
    __shared__ _Float16 WsH[128 * 32], WsL[128 * 32];
    const int tid = threadIdx.x;
    const int wave = tid >> 6;
    const int lane = tid & 63;
    const int wm = wave >> 1, wn = wave & 1;
    const int q  = lane >> 4;
    const int cl = lane & 15;
    const int l0  = blockIdx.x * 128;
    const int co0 = blockIdx.y * 128;
    const int b   = blockIdx.z;
    const float* inb = in + (size_t)b * C2V * L2V;

    floatx4 acc[4][4];
#pragma unroll
    for (int a = 0; a < 4; ++a)
#pragma unroll
        for (int n = 0; n < 4; ++n) acc[a][n] = (floatx4){0.f, 0.f, 0.f, 0.f};

    for (int ch = 0; ch < 64; ++ch) {
        __syncthreads();
        for (int n = tid; n < 4 * 264; n += 256) {
            int ci = n / 264;
            int m  = n - ci * 264;
            int p  = 2 * l0 - 4 + m;
            float v = (p >= 0 && p < L2V) ? inb[(size_t)(ch * 4 + ci) * L2V + p] * 1024.f : 0.f;
            _Float16 h = (_Float16)v;
            XsH[ci * 272 + m] = h;
            XsL[ci * 272 + m] = (_Float16)(v - (float)h);
        }
        const int k0 = ch * 32;
        for (int g = wave; g < 8; g += 4) {
            const _Float16* gh = WH + (size_t)(co0 + g * 16 + (lane >> 2)) * 2048 + k0 + (lane & 3) * 8;
            const _Float16* gl = WL + (size_t)(co0 + g * 16 + (lane >> 2)) * 2048 + k0 + (lane & 3) * 8;
            gload_lds16(gh, (char*)WsH + g * 1024);
            gload_lds16(gl, (char*)WsL + g * 1024);
        }
        asm volatile("s_waitcnt vmcnt(0)" ::: "memory");
        __syncthreads();

        half8 axh[4], axl[4], bwh[4], bwl[4];
#pragma unroll
        for (int a = 0; a < 4; ++a) {
            const int lrel = wm * 64 + a * 16 + cl;
            axh[a] = lds_read_half8_a4(&XsH[q * 272 + 2 * lrel]);
            axl[a] = lds_read_half8_a4(&XsL[q * 272 + 2 * lrel]);
        }
#pragma unroll
        for (int n = 0; n < 4; ++n) {
            const int ro = (wn * 64 + n * 16 + cl) * 32 + q * 8;
            bwh[n] = *(const half8*)&WsH[ro];
            bwl[n] = *(const half8*)&WsL[ro];
        }
#pragma unroll
        for (int a = 0; a < 4; ++a)
#pragma unroll
            for (int n = 0; n < 4; ++n) {
                acc[a][n] = __builtin_amdgcn_mfma_f32_16x16x32_f16(axh[a], bwh[n], acc[a][n], 0, 0, 0);
                acc[a][n] = __builtin_amdgcn_mfma_f32_16x16x32_f16(axl[a], bwh[n], acc[a][n], 0, 0, 0);
                acc[a][n] = __builtin_amdgcn_mfma_f32_16x16x32_f16(axh[a], bwl[n], acc[a][n], 0, 0, 0);
            }
    }

    float bv[4];
#pragma unroll
    for (int n = 0; n < 4; ++n) bv[n] = bias[co0 + wn * 64 + n * 16 + cl];
#pragma unroll
    for (int a = 0; a < 4; ++a)
#pragma unroll
        for (int n = 0; n < 4; ++n) {
            const int co = co0 + wn * 64 + n * 16 + cl;
#pragma unroll
            for (int r = 0; r < 4; ++r) {
                const int l = l0 + wm * 64 + a * 16 + q * 4 + r;
                float f = acc[a][n][r] * (1.f / 1048576.f) + bv[n];
                float s = f * 1024.f;
                _Float16 h = (_Float16)s;
                _Float16 lo = (_Float16)(s - (float)h);
                _Float16* dst = outh + ((size_t)b * L3V + l) * 1024 + co;
                dst[0] = h;
                dst[512] = lo;
            }
        }
}

// ---------------- row sum of squares * 2^19 (codebook) ----------------
__global__ void rowsq_scale_kernel(const float* __restrict__ src, float* __restrict__ dst) {
    const int r = blockIdx.x;
    const int lane = threadIdx.x;  // 64
    const float* row = src + (size_t)r * 512;
    float4 a = *(const float4*)&row[lane * 8];
    float4 c = *(const float4*)&row[lane * 8 + 4];
    float s = a.x * a.x + a.y * a.y + a.z * a.z + a.w * a.w
            + c.x * c.x + c.y * c.y + c.z * c.z + c.w * c.w;
#pragma unroll
    for (int off = 32; off > 0; off >>= 1) s += __shfl_down(s, off, 64);
    if (lane == 0) dst[r] = s * 524288.f;  // 2^19
}

// ---------------- fp32 -> scaled f16 hi/lo split (codebook) ----------------
__global__ void split_f16_kernel(const float* __restrict__ x, _Float16* __restrict__ y) {
    const int r = blockIdx.x;
    const int t = threadIdx.x;  // 128 threads x 4 elems
    const float4 v = *(const float4*)(x + (size_t)r * 512 + t * 4);
    float a0 = v.x * 1024.f, a1 = v.y * 1024.f, a2 = v.z * 1024.f, a3 = v.w * 1024.f;
    _Float16 h0 = (_Float16)a0, h1 = (_Float16)a1, h2 = (_Float16)a2, h3 = (_Float16)a3;
    typedef _Float16 half4v __attribute__((ext_vector_type(4)));
    half4v hv = {h0, h1, h2, h3};
    half4v lv = {(_Float16)(a0 - (float)h0), (_Float16)(a1 - (float)h1),
                 (_Float16)(a2 - (float)h2), (_Float16)(a3 - (float)h3)};
    *(half4v*)(y + (size_t)r * 1024 + t * 4) = hv;
    *(half4v*)(y + (size_t)r * 1024 + 512 + t * 4) = lv;
}

// ---------------- MFMA cross-GEMM + fused argmin (flattened 3-product K loop) ----
__global__ __launch_bounds__(256, 3) void cross_mfma_kernel(
    const _Float16* __restrict__ Af, const _Float16* __restrict__ Bf,
    const float* __restrict__ c2p,
    float* __restrict__ candv, int* __restrict__ candi) {

    __shared__ _Float16 AsH[4096], AsL[4096], BsH[4096], BsL[4096];

    const int tid  = threadIdx.x;
    const int wave = tid >> 6;
    const int lane = tid & 63;
    const int wm = wave >> 1, wn = wave & 1;
    const int q  = lane >> 4;
    const int cl = lane & 15;

    const int lt = blockIdx.x >> 1;
    const int vh = blockIdx.x & 1;
    const int l0 = lt * 128;
    const int k  = blockIdx.y;
    const int b  = blockIdx.z;

    const _Float16* Ab = Af + (size_t)(b * L3V + l0) * 1024;
    const _Float16* Bb = Bf + ((size_t)k * VOCABV + vh * 1024) * 1024;

    const int rowA = tid >> 2;
    const int seg  = tid & 3;

    char* dAH0 = (char*)AsH + wave * 1024; char* dAH1 = dAH0 + 4096;
    char* dAL0 = (char*)AsL + wave * 1024; char* dAL1 = dAL0 + 4096;
    char* dBH0 = (char*)BsH + wave * 1024; char* dBH1 = dBH0 + 4096;
    char* dBL0 = (char*)BsL + wave * 1024; char* dBL1 = dBL0 + 4096;

    float maxv[4][4];
    int   maxi[4][4];
#pragma unroll
    for (int a = 0; a < 4; ++a)
#pragma unroll
        for (int r = 0; r < 4; ++r) { maxv[a][r] = -3.4e38f; maxi[a][r] = 0; }

    for (int vt = 0; vt < 8; ++vt) {
        const _Float16* Bt = Bb + (size_t)(vt * 128) * 1024;
        floatx4 acc[4][4];
#pragma unroll
        for (int a = 0; a < 4; ++a)
#pragma unroll
            for (int n = 0; n < 4; ++n) acc[a][n] = (floatx4){0.f, 0.f, 0.f, 0.f};

#pragma unroll 1
        for (int ko = 0; ko < 512; ko += 32) {
            __syncthreads();
            const _Float16* ga = Ab + (size_t)rowA * 1024 + ko + seg * 8;
            const _Float16* gb = Bt + (size_t)rowA * 1024 + ko + seg * 8;
            gload_lds16(ga,               dAH0);
            gload_lds16(ga + 64 * 1024,   dAH1);
            gload_lds16(ga + 512,         dAL0);
            gload_lds16(ga + 512 + 64 * 1024, dAL1);
            gload_lds16(gb,               dBH0);
            gload_lds16(gb + 64 * 1024,   dBH1);
            gload_lds16(gb + 512,         dBL0);
            gload_lds16(gb + 512 + 64 * 1024, dBL1);
            asm volatile("s_waitcnt vmcnt(0)" ::: "memory");
            __syncthreads();

            half8 afh[4], afl[4], bfh[4], bfl[4];
#pragma unroll
            for (int a = 0; a < 4; ++a) {
                const int ro = (wm * 64 + a * 16 + cl) * 32 + q * 8;
                afh[a] = *(const half8*)&AsH[ro];
                afl[a] = *(const half8*)&AsL[ro];
            }
#pragma unroll
            for (int n = 0; n < 4; ++n) {
                const int ro = (wn * 64 + n * 16 + cl) * 32 + q * 8;
                bfh[n] = *(const half8*)&BsH[ro];
                bfl[n] = *(const half8*)&BsL[ro];
            }
#pragma unroll
            for (int a = 0; a < 4; ++a)
#pragma unroll
                for (int n = 0; n < 4; ++n) {
                    acc[a][n] = __builtin_amdgcn_mfma_f32_16x16x32_f16(afh[a], bfh[n], acc[a][n], 0, 0, 0);
                    acc[a][n] = __builtin_amdgcn_mfma_f32_16x16x32_f16(afl[a], bfh[n], acc[a][n], 0, 0, 0);
                    acc[a][n] = __builtin_amdgcn_mfma_f32_16x16x32_f16(afh[a], bfl[n], acc[a][n], 0, 0, 0);
                }
        }

        const int vbase = vh * 1024 + vt * 128 + wn * 64 + cl;
        float c2v[4];
#pragma unroll
        for (int n = 0; n < 4; ++n) c2v[n] = c2p[k * VOCABV + vbase + n * 16];
#pragma unroll
        for (int a = 0; a < 4; ++a)
#pragma unroll
            for (int n = 0; n < 4; ++n) {
                const int vidx = vbase + n * 16;
#pragma unroll
                for (int r = 0; r < 4; ++r) {
                    float m = acc[a][n][r] - c2v[n];
                    if (m > maxv[a][r]) { maxv[a][r] = m; maxi[a][r] = vidx; }
                }
            }
    }

#pragma unroll
    for (int a = 0; a < 4; ++a)
#pragma unroll
        for (int r = 0; r < 4; ++r) {
            float v = maxv[a][r]; int idx = maxi[a][r];
#pragma unroll
            for (int m = 1; m < 16; m <<= 1) {
                float ov = __shfl_xor(v, m, 64);
                int   oi = __shfl_xor(idx, m, 64);
                if (ov > v || (ov == v && oi < idx)) { v = ov; idx = oi; }
            }
            maxv[a][r] = v; maxi[a][r] = idx;
        }

    __syncthreads();
    float* redv = (float*)AsH;   // [128][2]
    int*   redi = (int*)BsH;
    if (cl == 0) {
#pragma unroll
        for (int a = 0; a < 4; ++a)
#pragma unroll
            for (int r = 0; r < 4; ++r) {
                int row = wm * 64 + a * 16 + q * 4 + r;
                redv[row * 2 + wn] = maxv[a][r];
                redi[row * 2 + wn] = maxi[a][r];
            }
    }
    __syncthreads();
    if (tid < 128) {
        float v0 = redv[tid * 2], v1 = redv[tid * 2 + 1];
        int   i0 = redi[tid * 2], i1 = redi[tid * 2 + 1];
        bool t1 = (v1 > v0) || (v1 == v0 && i1 < i0);
        float bv = t1 ? v1 : v0;
        int   bi = t1 ? i1 : i0;
        size_t o = (size_t)vh * (B_ * KCB * L3V) + ((size_t)(b * KCB + k)) * L3V + l0 + tid;
        candv[o] = bv;
        candi[o] = bi;
    }
}

// ---------------- fused merge (two v-halves) + token write + embedding mean --------
__global__ void emb_merge_kernel(const float* __restrict__ cv, const int* __restrict__ ci,
                                 const float* __restrict__ E, float* __restrict__ out_tok,
                                 float* __restrict__ out_emb) {
    const int l = blockIdx.x;
    const int b = blockIdx.y;
    const int tid = threadIdx.x;  // 128
    __shared__ int tk[4];
    if (tid < 4) {
        const int n = (b * KCB + tid) * L3V + l;
        float v0 = cv[n], v1 = cv[B_ * KCB * L3V + n];
        int   i0 = ci[n], i1 = ci[B_ * KCB * L3V + n];
        bool t1 = (v1 > v0);  // half1 indices always larger: ties keep half0
        int best = t1 ? i1 : i0;
        tk[tid] = best;
        out_tok[n] = (float)best;
    }
    __syncthreads();
    const int h4 = tid * 4;
    const float4 e0 = *(const float4*)&E[(size_t)tk[0] * 512 + h4];
    const float4 e1 = *(const float4*)&E[(size_t)tk[1] * 512 + h4];
    const float4 e2 = *(const float4*)&E[(size_t)tk[2] * 512 + h4];
    const float4 e3 = *(const float4*)&E[(size_t)tk[3] * 512 + h4];
    float4 r;
    r.x = (e0.x + e1.x + e2.x + e3.x) * 0.25f;
    r.y = (e0.y + e1.y + e2.y + e3.y) * 0.25f;
    r.z = (e0.z + e1.z + e2.z + e3.z) * 0.25f;
    r.w = (e0.w + e1.w + e2.w + e3.w) * 0.25f;
    *(float4*)&out_emb[((size_t)b * L3V + l) * 512 + h4] = r;
}

extern "C" void kernel_launch(void* const* d_in, const int* in_sizes, int n_in,
                              void* d_out, int out_size, void* d_ws, size_t ws_size,
                              hipStream_t stream) {
    const float* audio = (const float*)d_in[0];
    const float* w1 = (const float*)d_in[1];
    const float* b1 = (const float*)d_in[2];
    const float* w2 = (const float*)d_in[3];
    const float* b2 = (const float*)d_in[4];
    const float* w3 = (const float*)d_in[5];
    const float* b3 = (const float*)d_in[6];
    const float* cb = (const float*)d_in[7];
    const float* E  = (const float*)d_in[8];

    float* out_tok = (float*)d_out;
    float* out_emb = out_tok + (size_t)B_ * KCB * L3V;

    float* ws = (float*)d_ws;
    size_t off = 0;
    float* x1  = ws + off; off += (size_t)B_ * C1V * L1V;            // 8.39M fl: conv1 out, later Afh
    float* x2f = ws + off; off += (size_t)B_ * C2V * L2V / 2;        // 4.19M fl: conv2 out [B][256][4096*2]
    float* bfh_f = ws + off; off += (size_t)KCB * VOCABV * 1024 / 2; // 4.19M fl: Bfh
    float* w2h_f = ws + off; off += (size_t)C2V * (C1V * 8) / 2;     // 131072 fl
    float* w2l_f = ws + off; off += (size_t)C2V * (C1V * 8) / 2;
    float* w3h_f = ws + off; off += (size_t)C3V * (C2V * 8) / 2;     // 524288 fl
    float* w3l_f = ws + off; off += (size_t)C3V * (C2V * 8) / 2;
    float* c2p = ws + off; off += (size_t)KCB * VOCABV;
    float* candv = ws + off; off += 2 * (size_t)B_ * KCB * L3V;
    int*   candi = (int*)(ws + off); off += 2 * (size_t)B_ * KCB * L3V;

    _Float16* Afh = (_Float16*)x1;   // conv3 writes over x1 (dead after conv2)
    _Float16* Bfh = (_Float16*)bfh_f;
    _Float16* W2H = (_Float16*)w2h_f; _Float16* W2L = (_Float16*)w2l_f;
    _Float16* W3H = (_Float16*)w3h_f; _Float16* W3L = (_Float16*)w3l_f;

    wsplit_kernel<<<(C2V * C1V + 255) / 256, 256, 0, stream>>>(w2, W2H, W2L, C1V, C2V);
    wsplit_kernel<<<(C3V * C2V + 255) / 256, 256, 0, stream>>>(w3, W3H, W3L, C2V, C3V);

    conv1_kernel<<<dim3(L1V / 256, C1V, B_), 256, 0, stream>>>(audio, w1, b1, x1);

    conv2_mfma_kernel<<<dim3(L2V / 128, C2V / 128, B_), 256, 0, stream>>>(
        x1, W2H, W2L, b2, x2f);

    conv3_mfma_kernel<<<dim3(L3V / 128, C3V / 128, B_), 256, 0, stream>>>(
        x2f, W3H, W3L, b3, Afh);

    rowsq_scale_kernel<<<KCB * VOCABV, 64, 0, stream>>>(cb, c2p);
    split_f16_kernel<<<KCB * VOCABV, 128, 0, stream>>>(cb, Bfh);

    cross_mfma_kernel<<<dim3(64, KCB, B_), 256, 0, stream>>>(Afh, Bfh, c2p, candv, candi);

    emb_merge_kernel<<<dim3(L3V, B_), 128, 0, stream>>>(candv, candi, E, out_tok, out_emb);
}

// Round 5
// 778.526 us; speedup vs baseline: 3.8609x; 1.0444x over previous
//
#include <hip/hip_runtime.h>
#include <hip/hip_bf16.h>
#include <stdint.h>

#define B_ 4
#define S_IN 32768
#define C1V 128
#define L1V 16384
#define C2V 256
#define L2V 8192
#define C3V 512
#define L3V 4096
#define VOCABV 2048
#define KCB 4

typedef _Float16 half8 __attribute__((ext_vector_type(8)));
typedef float floatx4 __attribute__((ext_vector_type(4)));

#define AS1 __attribute__((address_space(1)))
#define AS3 __attribute__((address_space(3)))

__device__ __forceinline__ void gload_lds16(const void* g, void* l) {
    __builtin_amdgcn_global_load_lds((const AS1 void*)g, (AS3 void*)l, 16, 0, 0);
}

// read 8 halfs at a 4B-aligned LDS address (4x ds_read_b32)
__device__ __forceinline__ half8 lds_read_half8_a4(const _Float16* p) {
    union { uint32_t u[4]; half8 h; } t;
    const uint32_t* w = (const uint32_t*)p;
    t.u[0] = w[0]; t.u[1] = w[1]; t.u[2] = w[2]; t.u[3] = w[3];
    return t.h;
}

// ---------------- conv1: [B,1,S] -> [B,128,16384], k=7 s=2 p=3, relu ----------------
__global__ void conv1_kernel(const float* __restrict__ x, const float* __restrict__ w,
                             const float* __restrict__ bias, float* __restrict__ out) {
    __shared__ float xs[2 * 256 + 6];
    __shared__ float ws[7];
    const int l0 = blockIdx.x * 256;
    const int co = blockIdx.y;
    const int b  = blockIdx.z;
    const int tid = threadIdx.x;
    const float* xb = x + (size_t)b * S_IN;
    for (int n = tid; n < 2 * 256 + 6; n += 256) {
        int p = 2 * l0 - 3 + n;
        xs[n] = (p >= 0 && p < S_IN) ? xb[p] : 0.f;
    }
    if (tid < 7) ws[tid] = w[co * 7 + tid];
    __syncthreads();
    float acc = bias[co];
    const int base = 2 * tid;
#pragma unroll
    for (int t = 0; t < 7; ++t) acc = fmaf(ws[t], xs[base + t], acc);
    acc = fmaxf(acc, 0.f);
    out[((size_t)(b * C1V + co)) * L1V + l0 + tid] = acc;
}

// ---------------- weight prep: w[co][ci][7] fp32 -> hi/lo f16 planes [co][ci*8+u] ----
__global__ void wsplit_kernel(const float* __restrict__ w, _Float16* __restrict__ wh,
                              _Float16* __restrict__ wl, int cin, int cout) {
    int idx = blockIdx.x * 256 + threadIdx.x;
    if (idx >= cin * cout) return;
    int co = idx / cin;
    int ci = idx - co * cin;
    const float* src = w + ((size_t)co * cin + ci) * 7;
    half8 h, l;
    h[0] = (_Float16)0.f; l[0] = (_Float16)0.f;
#pragma unroll
    for (int u = 1; u < 8; ++u) {
        float v = src[u - 1] * 1024.f;
        _Float16 hh = (_Float16)v;
        h[u] = hh;
        l[u] = (_Float16)(v - (float)hh);
    }
    size_t o = (size_t)co * (cin * 8) + ci * 8;
    *(half8*)(wh + o) = h;
    *(half8*)(wl + o) = l;
}

// ---------------- conv2 via f16 3-product MFMA: A=W (m=co), B=X windows (n=l) -------
__global__ __launch_bounds__(256, 2) void conv2_mfma_kernel(
    const float* __restrict__ in, const _Float16* __restrict__ WH,
    const _Float16* __restrict__ WL, const float* __restrict__ bias,
    float* __restrict__ out) {
    __shared__ _Float16 XsH[4 * 272], XsL[4 * 272];
    __shared__ _Float16 WsH[128 * 32], WsL[128 * 32];
    const int tid = threadIdx.x;
    const int wave = tid >> 6;
    const int lane = tid & 63;
    const int wm = wave >> 1, wn = wave & 1;
    const int q  = lane >> 4;
    const int cl = lane & 15;
    const int l0  = blockIdx.x * 128;
    const int co0 = blockIdx.y * 128;
    const int b   = blockIdx.z;
    const float* inb = in + (size_t)b * C1V * L1V;

    floatx4 acc[4][4];
#pragma unroll
    for (int a = 0; a < 4; ++a)
#pragma unroll
        for (int n = 0; n < 4; ++n) acc[a][n] = (floatx4){0.f, 0.f, 0.f, 0.f};

    for (int ch = 0; ch < 32; ++ch) {
        __syncthreads();
        for (int n = tid; n < 4 * 264; n += 256) {
            int ci = n / 264;
            int m  = n - ci * 264;
            int p  = 2 * l0 - 4 + m;
            float v = (p >= 0 && p < L1V) ? inb[(size_t)(ch * 4 + ci) * L1V + p] * 1024.f : 0.f;
            _Float16 h = (_Float16)v;
            XsH[ci * 272 + m] = h;
            XsL[ci * 272 + m] = (_Float16)(v - (float)h);
        }
        const int k0 = ch * 32;
        for (int g = wave; g < 8; g += 4) {
            const _Float16* gh = WH + (size_t)(co0 + g * 16 + (lane >> 2)) * 1024 + k0 + (lane & 3) * 8;
            const _Float16* gl = WL + (size_t)(co0 + g * 16 + (lane >> 2)) * 1024 + k0 + (lane & 3) * 8;
            gload_lds16(gh, (char*)WsH + g * 1024);
            gload_lds16(gl, (char*)WsL + g * 1024);
        }
        asm volatile("s_waitcnt vmcnt(0)" ::: "memory");
        __syncthreads();

        half8 awh[4], awl[4], bxh[4], bxl[4];
#pragma unroll
        for (int a = 0; a < 4; ++a) {
            const int ro = (wm * 64 + a * 16 + cl) * 32 + q * 8;
            awh[a] = *(const half8*)&WsH[ro];
            awl[a] = *(const half8*)&WsL[ro];
        }
#pragma unroll
        for (int n = 0; n < 4; ++n) {
            const int lrel = wn * 64 + n * 16 + cl;
            bxh[n] = lds_read_half8_a4(&XsH[q * 272 + 2 * lrel]);
            bxl[n] = lds_read_half8_a4(&XsL[q * 272 + 2 * lrel]);
        }
#pragma unroll
        for (int a = 0; a < 4; ++a)
#pragma unroll
            for (int n = 0; n < 4; ++n) {
                acc[a][n] = __builtin_amdgcn_mfma_f32_16x16x32_f16(awh[a], bxh[n], acc[a][n], 0, 0, 0);
                acc[a][n] = __builtin_amdgcn_mfma_f32_16x16x32_f16(awl[a], bxh[n], acc[a][n], 0, 0, 0);
                acc[a][n] = __builtin_amdgcn_mfma_f32_16x16x32_f16(awh[a], bxl[n], acc[a][n], 0, 0, 0);
            }
    }

    float bv[4][4];
#pragma unroll
    for (int a = 0; a < 4; ++a)
#pragma unroll
        for (int r = 0; r < 4; ++r) bv[a][r] = bias[co0 + wm * 64 + a * 16 + q * 4 + r];
#pragma unroll
    for (int a = 0; a < 4; ++a)
#pragma unroll
        for (int n = 0; n < 4; ++n) {
            const int l = l0 + wn * 64 + n * 16 + cl;
#pragma unroll
            for (int r = 0; r < 4; ++r) {
                const int co = co0 + wm * 64 + a * 16 + q * 4 + r;
                float vv = fmaxf(acc[a][n][r] * (1.f / 1048576.f) + bv[a][r], 0.f);
                out[((size_t)(b * C2V + co)) * L2V + l] = vv;
            }
        }
}

// ---------------- conv3 via f16 3-product MFMA: A=X windows (m=l), B=W (n=co) -------
__global__ __launch_bounds__(256, 2) void conv3_mfma_kernel(
    const float* __restrict__ in, const _Float16* __restrict__ WH,
    const _Float16* __restrict__ WL, const float* __restrict__ bias,
    _Float16* __restrict__ outh) {
    __shared__ _Float16 XsH[4 * 272], XsL[4 * 272];
    __shared__ _Float16 WsH[128 * 32], WsL[128 * 32];
    const int tid = threadIdx.x;
    const int wave = tid >> 6;
    const int lane = tid & 63;
    const int wm = wave >> 1, wn = wave & 1;
    const int q  = lane >> 4;
    const int cl = lane & 15;
    const int l0  = blockIdx.x * 128;
    const int co0 = blockIdx.y * 128;
    const int b   = blockIdx.z;
    const float* inb = in + (size_t)b * C2V * L2V;

    floatx4 acc[4][4];
#pragma unroll
    for (int a = 0; a < 4; ++a)
#pragma unroll
        for (int n = 0; n < 4; ++n) acc[a][n] = (floatx4){0.f, 0.f, 0.f, 0.f};

    for (int ch = 0; ch < 64; ++ch) {
        __syncthreads();
        for (int n = tid; n < 4 * 264; n += 256) {
            int ci = n / 264;
            int m  = n - ci * 264;
            int p  = 2 * l0 - 4 + m;
            float v = (p >= 0 && p < L2V) ? inb[(size_t)(ch * 4 + ci) * L2V + p] * 1024.f : 0.f;
            _Float16 h = (_Float16)v;
            XsH[ci * 272 + m] = h;
            XsL[ci * 272 + m] = (_Float16)(v - (float)h);
        }
        const int k0 = ch * 32;
        for (int g = wave; g < 8; g += 4) {
            const _Float16* gh = WH + (size_t)(co0 + g * 16 + (lane >> 2)) * 2048 + k0 + (lane & 3) * 8;
            const _Float16* gl = WL + (size_t)(co0 + g * 16 + (lane >> 2)) * 2048 + k0 + (lane & 3) * 8;
            gload_lds16(gh, (char*)WsH + g * 1024);
            gload_lds16(gl, (char*)WsL + g * 1024);
        }
        asm volatile("s_waitcnt vmcnt(0)" ::: "memory");
        __syncthreads();

        half8 axh[4], axl[4], bwh[4], bwl[4];
#pragma unroll
        for (int a = 0; a < 4; ++a) {
            const int lrel = wm * 64 + a * 16 + cl;
            axh[a] = lds_read_half8_a4(&XsH[q * 272 + 2 * lrel]);
            axl[a] = lds_read_half8_a4(&XsL[q * 272 + 2 * lrel]);
        }
#pragma unroll
        for (int n = 0; n < 4; ++n) {
            const int ro = (wn * 64 + n * 16 + cl) * 32 + q * 8;
            bwh[n] = *(const half8*)&WsH[ro];
            bwl[n] = *(const half8*)&WsL[ro];
        }
#pragma unroll
        for (int a = 0; a < 4; ++a)
#pragma unroll
            for (int n = 0; n < 4; ++n) {
                acc[a][n] = __builtin_amdgcn_mfma_f32_16x16x32_f16(axh[a], bwh[n], acc[a][n], 0, 0, 0);
                acc[a][n] = __builtin_amdgcn_mfma_f32_16x16x32_f16(axl[a], bwh[n], acc[a][n], 0, 0, 0);
                acc[a][n] = __builtin_amdgcn_mfma_f32_16x16x32_f16(axh[a], bwl[n], acc[a][n], 0, 0, 0);
            }
    }

    float bv[4];
#pragma unroll
    for (int n = 0; n < 4; ++n) bv[n] = bias[co0 + wn * 64 + n * 16 + cl];
#pragma unroll
    for (int a = 0; a < 4; ++a)
#pragma unroll
        for (int n = 0; n < 4; ++n) {
            const int co = co0 + wn * 64 + n * 16 + cl;
#pragma unroll
            for (int r = 0; r < 4; ++r) {
                const int l = l0 + wm * 64 + a * 16 + q * 4 + r;
                float f = acc[a][n][r] * (1.f / 1048576.f) + bv[n];
                float s = f * 1024.f;
                _Float16 h = (_Float16)s;
                _Float16 lo = (_Float16)(s - (float)h);
                _Float16* dst = outh + ((size_t)b * L3V + l) * 1024 + co;
                dst[0] = h;
                dst[512] = lo;
            }
        }
}

// ---------------- fused codebook prep: rowsq*2^19 + x1024 hi/lo f16 split ----------
__global__ void cbprep_kernel(const float* __restrict__ cb, _Float16* __restrict__ y,
                              float* __restrict__ c2p) {
    const int r = blockIdx.x;
    const int lane = threadIdx.x;  // 64
    const float* row = cb + (size_t)r * 512;
    float4 a = *(const float4*)&row[lane * 8];
    float4 c = *(const float4*)&row[lane * 8 + 4];
    float s = a.x * a.x + a.y * a.y + a.z * a.z + a.w * a.w
            + c.x * c.x + c.y * c.y + c.z * c.z + c.w * c.w;
#pragma unroll
    for (int off = 32; off > 0; off >>= 1) s += __shfl_down(s, off, 64);
    if (lane == 0) c2p[r] = s * 524288.f;  // 2^19

    const float e[8] = {a.x, a.y, a.z, a.w, c.x, c.y, c.z, c.w};
    half8 hv, lv;
#pragma unroll
    for (int i = 0; i < 8; ++i) {
        float v = e[i] * 1024.f;
        _Float16 h = (_Float16)v;
        hv[i] = h;
        lv[i] = (_Float16)(v - (float)h);
    }
    *(half8*)(y + (size_t)r * 1024 + lane * 8) = hv;
    *(half8*)(y + (size_t)r * 1024 + 512 + lane * 8) = lv;
}

// ---------------- MFMA cross-GEMM + fused argmin, 128l x 256v block tile -----------
// Wave tile 64l x 128v (acc 4x8). Full V=2048 per block over 8 vt iterations.
// acc = Ahi*Bhi + Alo*Bhi + Ahi*Blo = 2^20*cross; key = acc - c2*2^19 (argmax).
__global__ __launch_bounds__(256, 2) void cross_mfma_kernel(
    const _Float16* __restrict__ Af, const _Float16* __restrict__ Bf,
    const float* __restrict__ c2p,
    int* __restrict__ tok_i, float* __restrict__ tok_f) {

    __shared__ _Float16 AsH[128 * 32], AsL[128 * 32];   // 8 KB each
    __shared__ _Float16 BsH[256 * 32], BsL[256 * 32];   // 16 KB each
    __shared__ float slotv[2][128];
    __shared__ int   sloti[2][128];

    const int tid  = threadIdx.x;
    const int wave = tid >> 6;
    const int lane = tid & 63;
    const int wm = wave >> 1, wn = wave & 1;
    const int q  = lane >> 4;
    const int cl = lane & 15;

    const int l0 = blockIdx.x * 128;
    const int k  = blockIdx.y;
    const int b  = blockIdx.z;

    const _Float16* Ab = Af + (size_t)(b * L3V + l0) * 1024;
    const _Float16* Bb = Bf + (size_t)k * VOCABV * 1024;

    if (tid < 128) {
        slotv[0][tid] = -3.4e38f; slotv[1][tid] = -3.4e38f;
        sloti[0][tid] = 0;        sloti[1][tid] = 0;
    }

    const int rsub = tid >> 2;       // 0..63: row within 64-row staging group
    const int seg  = tid & 3;        // 16B segment within 64B row

#pragma unroll 1
    for (int vt = 0; vt < 8; ++vt) {
        const _Float16* Bt = Bb + (size_t)(vt * 256) * 1024;
        floatx4 acc[4][8];
#pragma unroll
        for (int mt = 0; mt < 4; ++mt)
#pragma unroll
            for (int nt = 0; nt < 8; ++nt) acc[mt][nt] = (floatx4){0.f, 0.f, 0.f, 0.f};

#pragma unroll 1
        for (int ko = 0; ko < 512; ko += 32) {
            __syncthreads();
#pragma unroll
            for (int i = 0; i < 2; ++i) {
                const _Float16* ga = Ab + (size_t)(i * 64 + rsub) * 1024 + ko + seg * 8;
                gload_lds16(ga,       (char*)AsH + i * 4096 + tid * 16);
                gload_lds16(ga + 512, (char*)AsL + i * 4096 + tid * 16);
            }
#pragma unroll
            for (int i = 0; i < 4; ++i) {
                const _Float16* gb = Bt + (size_t)(i * 64 + rsub) * 1024 + ko + seg * 8;
                gload_lds16(gb,       (char*)BsH + i * 4096 + tid * 16);
                gload_lds16(gb + 512, (char*)BsL + i * 4096 + tid * 16);
            }
            asm volatile("s_waitcnt vmcnt(0)" ::: "memory");
            __syncthreads();

            half8 ah[4], al[4];
#pragma unroll
            for (int mt = 0; mt < 4; ++mt) {
                const int ro = (wm * 64 + mt * 16 + cl) * 32 + q * 8;
                ah[mt] = *(const half8*)&AsH[ro];
                al[mt] = *(const half8*)&AsL[ro];
            }
#pragma unroll
            for (int nt = 0; nt < 8; ++nt) {
                const int ro = (wn * 128 + nt * 16 + cl) * 32 + q * 8;
                half8 bh = *(const half8*)&BsH[ro];
                half8 bl = *(const half8*)&BsL[ro];
#pragma unroll
                for (int mt = 0; mt < 4; ++mt) {
                    acc[mt][nt] = __builtin_amdgcn_mfma_f32_16x16x32_f16(ah[mt], bh, acc[mt][nt], 0, 0, 0);
                    acc[mt][nt] = __builtin_amdgcn_mfma_f32_16x16x32_f16(al[mt], bh, acc[mt][nt], 0, 0, 0);
                    acc[mt][nt] = __builtin_amdgcn_mfma_f32_16x16x32_f16(ah[mt], bl, acc[mt][nt], 0, 0, 0);
                }
            }
        }

        // per-vt argmax epilogue
        float c2v[8];
#pragma unroll
        for (int nt = 0; nt < 8; ++nt)
            c2v[nt] = c2p[k * VOCABV + vt * 256 + wn * 128 + nt * 16 + cl];
#pragma unroll
        for (int mt = 0; mt < 4; ++mt)
#pragma unroll
            for (int r = 0; r < 4; ++r) {
                float bv = acc[mt][0][r] - c2v[0];
                int   bi = vt * 256 + wn * 128 + cl;
#pragma unroll
                for (int nt = 1; nt < 8; ++nt) {
                    float m = acc[mt][nt][r] - c2v[nt];
                    int   vi = vt * 256 + wn * 128 + nt * 16 + cl;
                    if (m > bv) { bv = m; bi = vi; }
                }
#pragma unroll
                for (int msk = 1; msk < 16; msk <<= 1) {
                    float ov = __shfl_xor(bv, msk, 64);
                    int   oi = __shfl_xor(bi, msk, 64);
                    if (ov > bv || (ov == bv && oi < bi)) { bv = ov; bi = oi; }
                }
                if (cl == 0) {
                    const int row = wm * 64 + mt * 16 + q * 4 + r;
                    float cur = slotv[wn][row];
                    int   ci  = sloti[wn][row];
                    if (bv > cur || (bv == cur && bi < ci)) {
                        slotv[wn][row] = bv;
                        sloti[wn][row] = bi;
                    }
                }
            }
    }

    __syncthreads();
    if (tid < 128) {
        float v0 = slotv[0][tid], v1 = slotv[1][tid];
        int   i0 = sloti[0][tid], i1 = sloti[1][tid];
        bool t1 = (v1 > v0);  // wn=1 indices always larger: ties keep wn=0
        int best = t1 ? i1 : i0;
        const int n = (b * KCB + k) * L3V + l0 + tid;
        tok_i[n] = best;
        tok_f[n] = (float)best;
    }
}

// ---------------- embedding mean over 4 codebooks ----------------
__global__ void emb_kernel(const int* __restrict__ tokens, const float* __restrict__ E,
                           float* __restrict__ out) {
    const int l = blockIdx.x;
    const int b = blockIdx.y;
    const int h4 = threadIdx.x * 4;
    const int t0 = tokens[((size_t)(b * KCB + 0)) * L3V + l];
    const int t1 = tokens[((size_t)(b * KCB + 1)) * L3V + l];
    const int t2 = tokens[((size_t)(b * KCB + 2)) * L3V + l];
    const int t3 = tokens[((size_t)(b * KCB + 3)) * L3V + l];
    const float4 e0 = *(const float4*)&E[(size_t)t0 * 512 + h4];
    const float4 e1 = *(const float4*)&E[(size_t)t1 * 512 + h4];
    const float4 e2 = *(const float4*)&E[(size_t)t2 * 512 + h4];
    const float4 e3 = *(const float4*)&E[(size_t)t3 * 512 + h4];
    float4 r;
    r.x = (e0.x + e1.x + e2.x + e3.x) * 0.25f;
    r.y = (e0.y + e1.y + e2.y + e3.y) * 0.25f;
    r.z = (e0.z + e1.z + e2.z + e3.z) * 0.25f;
    r.w = (e0.w + e1.w + e2.w + e3.w) * 0.25f;
    *(float4*)&out[((size_t)b * L3V + l) * 512 + h4] = r;
}

extern "C" void kernel_launch(void* const* d_in, const int* in_sizes, int n_in,
                              void* d_out, int out_size, void* d_ws, size_t ws_size,
                              hipStream_t stream) {
    const float* audio = (const float*)d_in[0];
    const float* w1 = (const float*)d_in[1];
    const float* b1 = (const float*)d_in[2];
    const float* w2 = (const float*)d_in[3];
    const float* b2 = (const float*)d_in[4];
    const float* w3 = (const float*)d_in[5];
    const float* b3 = (const float*)d_in[6];
    const float* cb = (const float*)d_in[7];
    const float* E  = (const float*)d_in[8];

    float* out_tok = (float*)d_out;
    float* out_emb = out_tok + (size_t)B_ * KCB * L3V;

    float* ws = (float*)d_ws;
    size_t off = 0;
    float* x1  = ws + off; off += (size_t)B_ * C1V * L1V;            // conv1 out, later Afh
    float* x2f = ws + off; off += (size_t)B_ * C2V * L2V / 2;        // conv2 out
    float* bfh_f = ws + off; off += (size_t)KCB * VOCABV * 1024 / 2; // Bfh
    float* w2h_f = ws + off; off += (size_t)C2V * (C1V * 8) / 2;
    float* w2l_f = ws + off; off += (size_t)C2V * (C1V * 8) / 2;
    float* w3h_f = ws + off; off += (size_t)C3V * (C2V * 8) / 2;
    float* w3l_f = ws + off; off += (size_t)C3V * (C2V * 8) / 2;
    float* c2p = ws + off; off += (size_t)KCB * VOCABV;
    int*   tok = (int*)(ws + off); off += (size_t)B_ * KCB * L3V;

    _Float16* Afh = (_Float16*)x1;   // conv3 writes over x1 (dead after conv2)
    _Float16* Bfh = (_Float16*)bfh_f;
    _Float16* W2H = (_Float16*)w2h_f; _Float16* W2L = (_Float16*)w2l_f;
    _Float16* W3H = (_Float16*)w3h_f; _Float16* W3L = (_Float16*)w3l_f;

    wsplit_kernel<<<(C2V * C1V + 255) / 256, 256, 0, stream>>>(w2, W2H, W2L, C1V, C2V);
    wsplit_kernel<<<(C3V * C2V + 255) / 256, 256, 0, stream>>>(w3, W3H, W3L, C2V, C3V);

    conv1_kernel<<<dim3(L1V / 256, C1V, B_), 256, 0, stream>>>(audio, w1, b1, x1);

    conv2_mfma_kernel<<<dim3(L2V / 128, C2V / 128, B_), 256, 0, stream>>>(
        x1, W2H, W2L, b2, x2f);

    conv3_mfma_kernel<<<dim3(L3V / 128, C3V / 128, B_), 256, 0, stream>>>(
        x2f, W3H, W3L, b3, Afh);

    cbprep_kernel<<<KCB * VOCABV, 64, 0, stream>>>(cb, Bfh, c2p);

    cross_mfma_kernel<<<dim3(L3V / 128, KCB, B_), 256, 0, stream>>>(
        Afh, Bfh, c2p, tok, out_tok);

    emb_kernel<<<dim3(L3V, B_), 128, 0, stream>>>(tok, E, out_emb);
}